// Round 1
// baseline (698.447 us; speedup 1.0000x reference)
//
#include <hip/hip_runtime.h>
#include <math.h>

static constexpr int Bn = 32, Pn = 16384, Cn = 2, Sn = 256;

#define TWO_PI_F 6.28318530717958647692f

__device__ __forceinline__ float elu_f(float x) { return x > 0.0f ? x : expm1f(x); }

__device__ __forceinline__ void atomicAddF(float* p, float v) {
#if defined(__HIP_PLATFORM_AMD__)
  unsafeAtomicAdd(p, v);
#else
  atomicAdd(p, v);
#endif
}

// ---------------- 256-pt FFT in LDS, 64 threads -----------------
// twr/twi: e^{-2*pi*i*t/256}, t in [0,128)
__device__ __forceinline__ void fft256(float* re, float* im,
                                       const float* twr, const float* twi,
                                       int lane, bool inverse) {
  #pragma unroll
  for (int q = 0; q < 4; q++) {
    int t = lane + q * 64;
    int r = (int)(__brev((unsigned)t) >> 24);
    if (t < r) {
      float a = re[t]; re[t] = re[r]; re[r] = a;
      float b = im[t]; im[t] = im[r]; im[r] = b;
    }
  }
  __syncthreads();
  #pragma unroll
  for (int s = 1; s <= 8; s++) {
    int half = 1 << (s - 1);
    #pragma unroll
    for (int q = 0; q < 2; q++) {
      int bf = lane + q * 64;
      int j = bf & (half - 1);
      int grp = bf >> (s - 1);
      int i0 = (grp << s) + j;
      int i1 = i0 + half;
      int tx = j << (8 - s);
      float wr = twr[tx];
      float wi = twi[tx];
      if (inverse) wi = -wi;
      float xr = re[i1], xi = im[i1];
      float tr = fmaf(xr, wr, -xi * wi);
      float ti = fmaf(xr, wi,  xi * wr);
      float ar = re[i0], ai = im[i0];
      re[i0] = ar + tr; im[i0] = ai + ti;
      re[i1] = ar - tr; im[i1] = ai - ti;
    }
    __syncthreads();
  }
}

// ---------------- enc precompute: encpart[p][64] = enc(p) @ W_in[0:60] ------
__global__ __launch_bounds__(64) void enc_kernel(const float* __restrict__ mp,
                                                 const float* __restrict__ W_in,
                                                 float* __restrict__ encpart) {
  __shared__ float ebuf[60][64];
  int tid = threadIdx.x;
  int p = blockIdx.x * 64 + tid;
  #pragma unroll
  for (int c = 0; c < 3; c++) {
    float pos = mp[p * 3 + c];
    #pragma unroll
    for (int i = 0; i < 10; i++) {
      float freq = powf(128.0f, (float)i / 9.0f);
      float ang = (TWO_PI_F * pos) * freq;
      ebuf[c * 20 + i][tid]      = sinf(ang);
      ebuf[c * 20 + 10 + i][tid] = cosf(ang);
    }
  }
  float h[64];
  #pragma unroll
  for (int j = 0; j < 64; j++) h[j] = 0.0f;
  for (int k = 0; k < 60; k++) {
    float ek = ebuf[k][tid];
    const float* wr = W_in + k * 64;
    #pragma unroll
    for (int j = 0; j < 64; j++) h[j] = fmaf(ek, wr[j], h[j]);
  }
  float* o = encpart + (size_t)p * 64;
  #pragma unroll
  for (int j = 0; j < 64; j++) o[j] = h[j];
}

// ---------------- fused MLP + project + splat ----------------
__global__ __launch_bounds__(64) void mlp_splat_kernel(
    const float* __restrict__ encpart, const float* __restrict__ z,
    const float* __restrict__ W_in, const float* __restrict__ W_layers,
    const float* __restrict__ W_out1, const float* __restrict__ W_out2,
    const float* __restrict__ mp, const float* __restrict__ orient,
    const float* __restrict__ amp, const float* __restrict__ ampvar,
    float* __restrict__ splat, float* __restrict__ out_fp,
    float* __restrict__ out_disp) {
  __shared__ float hbuf[64][64];
  int tid = threadIdx.x;
  int g = blockIdx.x * 64 + tid;
  int b = g >> 14;         // g / Pn
  int p = g & (Pn - 1);

  float h[64];
  const float4* ep = reinterpret_cast<const float4*>(encpart + (size_t)p * 64);
  #pragma unroll
  for (int j4 = 0; j4 < 16; j4++) {
    float4 v = ep[j4];
    h[4 * j4 + 0] = v.x; h[4 * j4 + 1] = v.y;
    h[4 * j4 + 2] = v.z; h[4 * j4 + 3] = v.w;
  }
  // z part of input layer (zk is wave-uniform -> scalar)
  for (int k = 0; k < 10; k++) {
    float zk = z[b * 10 + k];
    const float* wr = W_in + (60 + k) * 64;
    #pragma unroll
    for (int j = 0; j < 64; j++) h[j] = fmaf(zk, wr[j], h[j]);
  }
  // hidden layers
  for (int L = 0; L < 4; L++) {
    #pragma unroll
    for (int j = 0; j < 64; j++) hbuf[j][tid] = h[j];
    const float* WL = W_layers + L * 4096;
    float hn[64];
    #pragma unroll
    for (int j = 0; j < 64; j++) hn[j] = 0.0f;
    #pragma unroll 2
    for (int k = 0; k < 64; k++) {
      float hk = hbuf[k][tid];
      const float* wr = WL + k * 64;
      #pragma unroll
      for (int j = 0; j < 64; j++) hn[j] = fmaf(hk, wr[j], hn[j]);
    }
    #pragma unroll
    for (int j = 0; j < 64; j++) h[j] = elu_f(hn[j]);
  }
  // head
  float o0 = 0.f, o1 = 0.f, o2 = 0.f;
  #pragma unroll
  for (int k = 0; k < 64; k++) {
    float hk = h[k];
    o0 = fmaf(hk, W_out1[k * 3 + 0], o0);
    o1 = fmaf(hk, W_out1[k * 3 + 1], o1);
    o2 = fmaf(hk, W_out1[k * 3 + 2], o2);
  }
  o0 = elu_f(o0); o1 = elu_f(o1); o2 = elu_f(o2);
  float d0 = o0 * W_out2[0] + o1 * W_out2[3] + o2 * W_out2[6];
  float d1 = o0 * W_out2[1] + o1 * W_out2[4] + o2 * W_out2[7];
  float d2 = o0 * W_out2[2] + o1 * W_out2[5] + o2 * W_out2[8];

  float m0 = mp[p * 3 + 0], m1 = mp[p * 3 + 1], m2 = mp[p * 3 + 2];
  float f0 = m0 + d0, f1 = m1 + d1, f2 = m2 + d2;

  size_t ob = ((size_t)b * Pn + p) * 3;
  out_disp[ob + 0] = d0; out_disp[ob + 1] = d1; out_disp[ob + 2] = d2;
  out_fp[ob + 0] = f0; out_fp[ob + 1] = f1; out_fp[ob + 2] = f2;

  const float* R = orient + b * 9;
  float px = R[0] * f0 + R[1] * f1 + R[2] * f2;
  float py = R[3] * f0 + R[4] * f1 + R[5] * f2;

  // amplitudes: amp * softmax(ampvar, axis=0)
  float a0 = ampvar[p], a1 = ampvar[Pn + p];
  float mx = fmaxf(a0, a1);
  float e0 = expf(a0 - mx), e1 = expf(a1 - mx);
  float inv = 1.0f / (e0 + e1);
  float w0 = amp[p] * e0 * inv;
  float w1 = amp[Pn + p] * e1 * inv;

  // bilinear splat
  float pxp = fminf(fmaxf((px + 0.5f) * 256.0f, 0.0f), 254.999f);
  float pyp = fminf(fmaxf((py + 0.5f) * 256.0f, 0.0f), 254.999f);
  int x0 = (int)floorf(pxp), y0 = (int)floorf(pyp);
  float fx = pxp - (float)x0, fy = pyp - (float)y0;
  int x1 = min(x0 + 1, 255), y1 = min(y0 + 1, 255);
  float w00 = (1.f - fx) * (1.f - fy), w10 = fx * (1.f - fy);
  float w01 = (1.f - fx) * fy,         w11 = fx * fy;
  float* img0 = splat + ((size_t)b * 2 + 0) * 65536;
  float* img1 = splat + ((size_t)b * 2 + 1) * 65536;
  int i00 = y0 * 256 + x0, i10 = y0 * 256 + x1;
  int i01 = y1 * 256 + x0, i11 = y1 * 256 + x1;
  atomicAddF(img0 + i00, w0 * w00); atomicAddF(img0 + i10, w0 * w10);
  atomicAddF(img0 + i01, w0 * w01); atomicAddF(img0 + i11, w0 * w11);
  atomicAddF(img1 + i00, w1 * w00); atomicAddF(img1 + i10, w1 * w10);
  atomicAddF(img1 + i01, w1 * w01); atomicAddF(img1 + i11, w1 * w11);
}

// ---------------- forward FFT along x, per (bc, y) row ----------------
__global__ __launch_bounds__(64) void fft_rows_fwd(const float* __restrict__ splat,
                                                   float2* __restrict__ ws1) {
  __shared__ float re[256], im[256], twr[128], twi[128];
  int lane = threadIdx.x;
  int bc = blockIdx.x >> 8, y = blockIdx.x & 255;
  for (int t = lane; t < 128; t += 64) {
    float ang = -TWO_PI_F * (float)t / 256.0f;
    twr[t] = cosf(ang); twi[t] = sinf(ang);
  }
  const float* row = splat + (size_t)bc * 65536 + (size_t)y * 256;
  #pragma unroll
  for (int q = 0; q < 4; q++) {
    int x = lane + q * 64;
    re[x] = row[x]; im[x] = 0.0f;
  }
  __syncthreads();
  fft256(re, im, twr, twi, lane, false);
  float2* orow = ws1 + (size_t)bc * 65536 + (size_t)y * 256;
  #pragma unroll
  for (int q = 0; q < 4; q++) {
    int k = lane + q * 64;
    orow[k] = make_float2(re[k], im[k]);
  }
}

// ---------------- in-place per-image 256x256 complex transpose ----------------
__global__ __launch_bounds__(256) void transpose_inplace(float2* __restrict__ data) {
  int img = blockIdx.x, task = blockIdx.y;
  int ti = 0, t = task;
  while (t >= 8 - ti) { t -= 8 - ti; ti++; }
  int tj = ti + t;
  __shared__ float2 ta[32][33];
  __shared__ float2 tb[32][33];
  int lx = threadIdx.x & 31, ly0 = threadIdx.x >> 5;
  float2* base = data + (size_t)img * 65536;
  if (ti == tj) {
    #pragma unroll
    for (int q = 0; q < 4; q++) {
      int ly = ly0 + q * 8;
      ta[ly][lx] = base[(size_t)(ti * 32 + ly) * 256 + ti * 32 + lx];
    }
    __syncthreads();
    #pragma unroll
    for (int q = 0; q < 4; q++) {
      int ly = ly0 + q * 8;
      base[(size_t)(ti * 32 + ly) * 256 + ti * 32 + lx] = ta[lx][ly];
    }
  } else {
    #pragma unroll
    for (int q = 0; q < 4; q++) {
      int ly = ly0 + q * 8;
      ta[ly][lx] = base[(size_t)(ti * 32 + ly) * 256 + tj * 32 + lx];
      tb[ly][lx] = base[(size_t)(tj * 32 + ly) * 256 + ti * 32 + lx];
    }
    __syncthreads();
    #pragma unroll
    for (int q = 0; q < 4; q++) {
      int ly = ly0 + q * 8;
      base[(size_t)(tj * 32 + ly) * 256 + ti * 32 + lx] = ta[lx][ly];
      base[(size_t)(ti * 32 + ly) * 256 + tj * 32 + lx] = tb[lx][ly];
    }
  }
}

// --------- middle: y-FFT both classes, filter-combine, phase_y, inverse y-FFT ----
// input ws1t layout [bc][kx][y]; output A2 layout [b][kx][y]
__global__ __launch_bounds__(64) void fft_mid(const float2* __restrict__ ws1t,
                                              float2* __restrict__ A2,
                                              const float* __restrict__ shift,
                                              const float* __restrict__ Aarr,
                                              const float* __restrict__ Bparr) {
  __shared__ float re0[256], im0[256], re1[256], im1[256], twr[128], twi[128];
  int lane = threadIdx.x;
  int b = blockIdx.x >> 8, kx = blockIdx.x & 255;
  for (int t = lane; t < 128; t += 64) {
    float ang = -TWO_PI_F * (float)t / 256.0f;
    twr[t] = cosf(ang); twi[t] = sinf(ang);
  }
  const float2* r0 = ws1t + ((size_t)b * 2 + 0) * 65536 + (size_t)kx * 256;
  const float2* r1 = ws1t + ((size_t)b * 2 + 1) * 65536 + (size_t)kx * 256;
  #pragma unroll
  for (int q = 0; q < 4; q++) {
    int i = lane + q * 64;
    float2 v0 = r0[i], v1 = r1[i];
    re0[i] = v0.x; im0[i] = v0.y;
    re1[i] = v1.x; im1[i] = v1.y;
  }
  __syncthreads();
  fft256(re0, im0, twr, twi, lane, false);
  fft256(re1, im1, twr, twi, lane, false);

  float A0 = Aarr[0], A1 = Aarr[1], B0 = Bparr[0], B1 = Bparr[1];
  float sy = shift[b * 2 + 1];
  float rx = (kx <= 128) ? (float)kx : (float)(256 - kx);
  #pragma unroll
  for (int q = 0; q < 4; q++) {
    int ky = lane + q * 64;
    float ry = (ky <= 128) ? (float)ky : (float)(256 - ky);
    float R = sqrtf(rx * rx + ry * ry);
    float FF0 = A0 * A0 * expf(-B0 * B0 * R);
    float FF1 = A1 * A1 * expf(-B1 * B1 * R);
    float Gr = FF0 * re0[ky] + FF1 * re1[ky];
    float Gi = FF0 * im0[ky] + FF1 * im1[ky];
    float fk = (float)((ky < 128) ? ky : ky - 256) / 256.0f;
    float th = -TWO_PI_F * fk * sy;
    float c = cosf(th), s = sinf(th);
    re0[ky] = Gr * c - Gi * s;
    im0[ky] = Gr * s + Gi * c;
  }
  __syncthreads();
  fft256(re0, im0, twr, twi, lane, true);
  const float inv = 1.0f / 256.0f;
  float2* orow = A2 + (size_t)b * 65536 + (size_t)kx * 256;
  #pragma unroll
  for (int q = 0; q < 4; q++) {
    int yy = lane + q * 64;
    orow[yy] = make_float2(re0[yy] * inv, im0[yy] * inv);
  }
}

// --------- final: phase_x, inverse x-FFT, write real ----------
// input A2t layout [b][y][kx]
__global__ __launch_bounds__(64) void fft_final(const float2* __restrict__ A2t,
                                                const float* __restrict__ shift,
                                                float* __restrict__ out_imgs) {
  __shared__ float re[256], im[256], twr[128], twi[128];
  int lane = threadIdx.x;
  int b = blockIdx.x >> 8, y = blockIdx.x & 255;
  for (int t = lane; t < 128; t += 64) {
    float ang = -TWO_PI_F * (float)t / 256.0f;
    twr[t] = cosf(ang); twi[t] = sinf(ang);
  }
  const float2* row = A2t + (size_t)b * 65536 + (size_t)y * 256;
  float sx = shift[b * 2 + 0];
  #pragma unroll
  for (int q = 0; q < 4; q++) {
    int k = lane + q * 64;
    float2 v = row[k];
    float fk = (float)((k < 128) ? k : k - 256) / 256.0f;
    float th = -TWO_PI_F * fk * sx;
    float c = cosf(th), s = sinf(th);
    re[k] = v.x * c - v.y * s;
    im[k] = v.x * s + v.y * c;
  }
  __syncthreads();
  fft256(re, im, twr, twi, lane, true);
  const float inv = 1.0f / 256.0f;
  float* orow = out_imgs + (size_t)b * 65536 + (size_t)y * 256;
  #pragma unroll
  for (int q = 0; q < 4; q++) {
    int x = lane + q * 64;
    orow[x] = re[x] * inv;
  }
}

// ---------------- launch ----------------
extern "C" void kernel_launch(void* const* d_in, const int* in_sizes, int n_in,
                              void* d_out, int out_size, void* d_ws, size_t ws_size,
                              hipStream_t stream) {
  (void)in_sizes; (void)n_in; (void)out_size; (void)ws_size;
  const float* z       = (const float*)d_in[0];
  const float* orient  = (const float*)d_in[1];
  const float* shift   = (const float*)d_in[2];
  const float* mp      = (const float*)d_in[3];
  const float* W_in    = (const float*)d_in[4];
  const float* W_layers= (const float*)d_in[5];
  const float* W_out1  = (const float*)d_in[6];
  const float* W_out2  = (const float*)d_in[7];
  const float* amp     = (const float*)d_in[8];
  const float* ampvar  = (const float*)d_in[9];
  const float* Aarr    = (const float*)d_in[10];
  const float* Bparr   = (const float*)d_in[11];

  char* ws = (char*)d_ws;
  float*  splat   = (float*)ws;                       // 16 MB  [B][C][S][S]
  float2* ws1     = (float2*)(ws + 16777216);         // 32 MB  [B*C][256][256] complex
  float*  encpart = (float*)(ws + 50331648);          //  4 MB  [P][64]
  float2* A2      = (float2*)ws;                      // alias (splat dead after fft_rows)

  float* out      = (float*)d_out;
  float* out_imgs = out;                              // [B][S][S]
  float* out_fp   = out + (size_t)Bn * Sn * Sn;       // [B][P][3]
  float* out_disp = out_fp + (size_t)Bn * Pn * 3;     // [B][P][3]

  hipMemsetAsync(splat, 0, 16777216, stream);
  enc_kernel<<<Pn / 64, 64, 0, stream>>>(mp, W_in, encpart);
  mlp_splat_kernel<<<(Bn * Pn) / 64, 64, 0, stream>>>(
      encpart, z, W_in, W_layers, W_out1, W_out2, mp, orient, amp, ampvar,
      splat, out_fp, out_disp);
  fft_rows_fwd<<<Bn * Cn * Sn, 64, 0, stream>>>(splat, ws1);
  transpose_inplace<<<dim3(Bn * Cn, 36), 256, 0, stream>>>(ws1);
  fft_mid<<<Bn * Sn, 64, 0, stream>>>(ws1, A2, shift, Aarr, Bparr);
  transpose_inplace<<<dim3(Bn, 36), 256, 0, stream>>>(A2);
  fft_final<<<Bn * Sn, 64, 0, stream>>>(A2, shift, out_imgs);
}

// Round 2
// 574.706 us; speedup vs baseline: 1.2153x; 1.2153x over previous
//
#include <hip/hip_runtime.h>
#include <math.h>

static constexpr int Bn = 32, Pn = 16384, Cn = 2, Sn = 256;

#define TWO_PI_F 6.28318530717958647692f

__device__ __forceinline__ float elu_f(float x) {
  return x > 0.0f ? x : (__expf(x) - 1.0f);
}

__device__ __forceinline__ void atomicAddF(float* p, float v) {
#if defined(__HIP_PLATFORM_AMD__)
  unsafeAtomicAdd(p, v);
#else
  atomicAdd(p, v);
#endif
}

// ---------------- 256-pt FFT in LDS, 64 threads -----------------
__device__ __forceinline__ void fft256(float* re, float* im,
                                       const float* twr, const float* twi,
                                       int lane, bool inverse) {
  #pragma unroll
  for (int q = 0; q < 4; q++) {
    int t = lane + q * 64;
    int r = (int)(__brev((unsigned)t) >> 24);
    if (t < r) {
      float a = re[t]; re[t] = re[r]; re[r] = a;
      float b = im[t]; im[t] = im[r]; im[r] = b;
    }
  }
  __syncthreads();
  #pragma unroll
  for (int s = 1; s <= 8; s++) {
    int half = 1 << (s - 1);
    #pragma unroll
    for (int q = 0; q < 2; q++) {
      int bf = lane + q * 64;
      int j = bf & (half - 1);
      int grp = bf >> (s - 1);
      int i0 = (grp << s) + j;
      int i1 = i0 + half;
      int tx = j << (8 - s);
      float wr = twr[tx];
      float wi = twi[tx];
      if (inverse) wi = -wi;
      float xr = re[i1], xi = im[i1];
      float tr = fmaf(xr, wr, -xi * wi);
      float ti = fmaf(xr, wi,  xi * wr);
      float ar = re[i0], ai = im[i0];
      re[i0] = ar + tr; im[i0] = ai + ti;
      re[i1] = ar - tr; im[i1] = ai - ti;
    }
    __syncthreads();
  }
}

// ---------------- enc precompute: encpart[p][64] = enc(p) @ W_in[0:60] ------
__global__ __launch_bounds__(64) void enc_kernel(const float* __restrict__ mp,
                                                 const float* __restrict__ W_in,
                                                 float* __restrict__ encpart) {
  __shared__ float ebuf[60][64];
  int tid = threadIdx.x;
  int p = blockIdx.x * 64 + tid;
  #pragma unroll
  for (int c = 0; c < 3; c++) {
    float pos = mp[p * 3 + c];
    #pragma unroll
    for (int i = 0; i < 10; i++) {
      float freq = powf(128.0f, (float)i / 9.0f);
      float ang = (TWO_PI_F * pos) * freq;
      ebuf[c * 20 + i][tid]      = sinf(ang);
      ebuf[c * 20 + 10 + i][tid] = cosf(ang);
    }
  }
  float h[64];
  #pragma unroll
  for (int j = 0; j < 64; j++) h[j] = 0.0f;
  for (int k = 0; k < 60; k++) {
    float ek = ebuf[k][tid];
    const float* wr = W_in + k * 64;
    #pragma unroll
    for (int j = 0; j < 64; j++) h[j] = fmaf(ek, wr[j], h[j]);
  }
  float* o = encpart + (size_t)p * 64;
  #pragma unroll
  for (int j = 0; j < 64; j++) o[j] = h[j];
}

// ---------------- fused MLP + project + splat (register-resident) ----------
__global__ __launch_bounds__(256, 2) void mlp_splat_kernel(
    const float* __restrict__ encpart, const float* __restrict__ z,
    const float* __restrict__ W_in, const float* __restrict__ W_layers,
    const float* __restrict__ W_out1, const float* __restrict__ W_out2,
    const float* __restrict__ mp, const float* __restrict__ orient,
    const float* __restrict__ amp, const float* __restrict__ ampvar,
    float* __restrict__ splat, float* __restrict__ out_fp,
    float* __restrict__ out_disp) {
  int tid = threadIdx.x;
  int g = blockIdx.x * 256 + tid;
  int b = g >> 14;         // g / Pn  (Pn=16384, 64 blocks per batch)
  int p = g & (Pn - 1);

  float h[64];
  const float4* ep = reinterpret_cast<const float4*>(encpart + (size_t)p * 64);
  #pragma unroll
  for (int j4 = 0; j4 < 16; j4++) {
    float4 v = ep[j4];
    h[4 * j4 + 0] = v.x; h[4 * j4 + 1] = v.y;
    h[4 * j4 + 2] = v.z; h[4 * j4 + 3] = v.w;
  }
  // z part of input layer (zk wave-uniform -> scalar ops)
  #pragma unroll
  for (int k = 0; k < 10; k++) {
    float zk = z[b * 10 + k];
    const float* wr = W_in + (60 + k) * 64;
    #pragma unroll
    for (int j = 0; j < 64; j++) h[j] = fmaf(zk, wr[j], h[j]);
  }
  // hidden layers: fully static k x j unroll, h/hn register-resident
  for (int L = 0; L < 4; L++) {
    const float* WL = W_layers + L * 4096;
    float hn[64];
    #pragma unroll
    for (int j = 0; j < 64; j++) hn[j] = 0.0f;
    #pragma unroll
    for (int k = 0; k < 64; k++) {
      float hk = h[k];
      const float* wr = WL + k * 64;
      #pragma unroll
      for (int j = 0; j < 64; j++) hn[j] = fmaf(hk, wr[j], hn[j]);
    }
    #pragma unroll
    for (int j = 0; j < 64; j++) h[j] = elu_f(hn[j]);
  }
  // head
  float o0 = 0.f, o1 = 0.f, o2 = 0.f;
  #pragma unroll
  for (int k = 0; k < 64; k++) {
    float hk = h[k];
    o0 = fmaf(hk, W_out1[k * 3 + 0], o0);
    o1 = fmaf(hk, W_out1[k * 3 + 1], o1);
    o2 = fmaf(hk, W_out1[k * 3 + 2], o2);
  }
  o0 = elu_f(o0); o1 = elu_f(o1); o2 = elu_f(o2);
  float d0 = o0 * W_out2[0] + o1 * W_out2[3] + o2 * W_out2[6];
  float d1 = o0 * W_out2[1] + o1 * W_out2[4] + o2 * W_out2[7];
  float d2 = o0 * W_out2[2] + o1 * W_out2[5] + o2 * W_out2[8];

  float m0 = mp[p * 3 + 0], m1 = mp[p * 3 + 1], m2 = mp[p * 3 + 2];
  float f0 = m0 + d0, f1 = m1 + d1, f2 = m2 + d2;

  size_t ob = ((size_t)b * Pn + p) * 3;
  out_disp[ob + 0] = d0; out_disp[ob + 1] = d1; out_disp[ob + 2] = d2;
  out_fp[ob + 0] = f0; out_fp[ob + 1] = f1; out_fp[ob + 2] = f2;

  const float* R = orient + b * 9;
  float px = R[0] * f0 + R[1] * f1 + R[2] * f2;
  float py = R[3] * f0 + R[4] * f1 + R[5] * f2;

  // amplitudes: amp * softmax(ampvar, axis=0)
  float a0 = ampvar[p], a1 = ampvar[Pn + p];
  float mx = fmaxf(a0, a1);
  float e0 = __expf(a0 - mx), e1 = __expf(a1 - mx);
  float inv = 1.0f / (e0 + e1);
  float w0 = amp[p] * e0 * inv;
  float w1 = amp[Pn + p] * e1 * inv;

  // bilinear splat
  float pxp = fminf(fmaxf((px + 0.5f) * 256.0f, 0.0f), 254.999f);
  float pyp = fminf(fmaxf((py + 0.5f) * 256.0f, 0.0f), 254.999f);
  int x0 = (int)floorf(pxp), y0 = (int)floorf(pyp);
  float fx = pxp - (float)x0, fy = pyp - (float)y0;
  int x1 = min(x0 + 1, 255), y1 = min(y0 + 1, 255);
  float w00 = (1.f - fx) * (1.f - fy), w10 = fx * (1.f - fy);
  float w01 = (1.f - fx) * fy,         w11 = fx * fy;
  float* img0 = splat + ((size_t)b * 2 + 0) * 65536;
  float* img1 = splat + ((size_t)b * 2 + 1) * 65536;
  int i00 = y0 * 256 + x0, i10 = y0 * 256 + x1;
  int i01 = y1 * 256 + x0, i11 = y1 * 256 + x1;
  atomicAddF(img0 + i00, w0 * w00); atomicAddF(img0 + i10, w0 * w10);
  atomicAddF(img0 + i01, w0 * w01); atomicAddF(img0 + i11, w0 * w11);
  atomicAddF(img1 + i00, w1 * w00); atomicAddF(img1 + i10, w1 * w10);
  atomicAddF(img1 + i01, w1 * w01); atomicAddF(img1 + i11, w1 * w11);
}

// ---------------- forward FFT along x, per (bc, y) row ----------------
__global__ __launch_bounds__(64) void fft_rows_fwd(const float* __restrict__ splat,
                                                   float2* __restrict__ ws1) {
  __shared__ float re[256], im[256], twr[128], twi[128];
  int lane = threadIdx.x;
  int bc = blockIdx.x >> 8, y = blockIdx.x & 255;
  for (int t = lane; t < 128; t += 64) {
    float ang = -TWO_PI_F * (float)t / 256.0f;
    twr[t] = cosf(ang); twi[t] = sinf(ang);
  }
  const float* row = splat + (size_t)bc * 65536 + (size_t)y * 256;
  #pragma unroll
  for (int q = 0; q < 4; q++) {
    int x = lane + q * 64;
    re[x] = row[x]; im[x] = 0.0f;
  }
  __syncthreads();
  fft256(re, im, twr, twi, lane, false);
  float2* orow = ws1 + (size_t)bc * 65536 + (size_t)y * 256;
  #pragma unroll
  for (int q = 0; q < 4; q++) {
    int k = lane + q * 64;
    orow[k] = make_float2(re[k], im[k]);
  }
}

// ---------------- in-place per-image 256x256 complex transpose ----------------
__global__ __launch_bounds__(256) void transpose_inplace(float2* __restrict__ data) {
  int img = blockIdx.x, task = blockIdx.y;
  int ti = 0, t = task;
  while (t >= 8 - ti) { t -= 8 - ti; ti++; }
  int tj = ti + t;
  __shared__ float2 ta[32][33];
  __shared__ float2 tb[32][33];
  int lx = threadIdx.x & 31, ly0 = threadIdx.x >> 5;
  float2* base = data + (size_t)img * 65536;
  if (ti == tj) {
    #pragma unroll
    for (int q = 0; q < 4; q++) {
      int ly = ly0 + q * 8;
      ta[ly][lx] = base[(size_t)(ti * 32 + ly) * 256 + ti * 32 + lx];
    }
    __syncthreads();
    #pragma unroll
    for (int q = 0; q < 4; q++) {
      int ly = ly0 + q * 8;
      base[(size_t)(ti * 32 + ly) * 256 + ti * 32 + lx] = ta[lx][ly];
    }
  } else {
    #pragma unroll
    for (int q = 0; q < 4; q++) {
      int ly = ly0 + q * 8;
      ta[ly][lx] = base[(size_t)(ti * 32 + ly) * 256 + tj * 32 + lx];
      tb[ly][lx] = base[(size_t)(tj * 32 + ly) * 256 + ti * 32 + lx];
    }
    __syncthreads();
    #pragma unroll
    for (int q = 0; q < 4; q++) {
      int ly = ly0 + q * 8;
      base[(size_t)(tj * 32 + ly) * 256 + ti * 32 + lx] = ta[lx][ly];
      base[(size_t)(ti * 32 + ly) * 256 + tj * 32 + lx] = tb[lx][ly];
    }
  }
}

// --------- middle: y-FFT both classes, filter-combine, phase_y, inverse y-FFT ----
__global__ __launch_bounds__(64) void fft_mid(const float2* __restrict__ ws1t,
                                              float2* __restrict__ A2,
                                              const float* __restrict__ shift,
                                              const float* __restrict__ Aarr,
                                              const float* __restrict__ Bparr) {
  __shared__ float re0[256], im0[256], re1[256], im1[256], twr[128], twi[128];
  int lane = threadIdx.x;
  int b = blockIdx.x >> 8, kx = blockIdx.x & 255;
  for (int t = lane; t < 128; t += 64) {
    float ang = -TWO_PI_F * (float)t / 256.0f;
    twr[t] = cosf(ang); twi[t] = sinf(ang);
  }
  const float2* r0 = ws1t + ((size_t)b * 2 + 0) * 65536 + (size_t)kx * 256;
  const float2* r1 = ws1t + ((size_t)b * 2 + 1) * 65536 + (size_t)kx * 256;
  #pragma unroll
  for (int q = 0; q < 4; q++) {
    int i = lane + q * 64;
    float2 v0 = r0[i], v1 = r1[i];
    re0[i] = v0.x; im0[i] = v0.y;
    re1[i] = v1.x; im1[i] = v1.y;
  }
  __syncthreads();
  fft256(re0, im0, twr, twi, lane, false);
  fft256(re1, im1, twr, twi, lane, false);

  float A0 = Aarr[0], A1 = Aarr[1], B0 = Bparr[0], B1 = Bparr[1];
  float sy = shift[b * 2 + 1];
  float rx = (kx <= 128) ? (float)kx : (float)(256 - kx);
  #pragma unroll
  for (int q = 0; q < 4; q++) {
    int ky = lane + q * 64;
    float ry = (ky <= 128) ? (float)ky : (float)(256 - ky);
    float R = sqrtf(rx * rx + ry * ry);
    float FF0 = A0 * A0 * __expf(-B0 * B0 * R);
    float FF1 = A1 * A1 * __expf(-B1 * B1 * R);
    float Gr = FF0 * re0[ky] + FF1 * re1[ky];
    float Gi = FF0 * im0[ky] + FF1 * im1[ky];
    float fk = (float)((ky < 128) ? ky : ky - 256) / 256.0f;
    float th = -TWO_PI_F * fk * sy;
    float c = __cosf(th), s = __sinf(th);
    re0[ky] = Gr * c - Gi * s;
    im0[ky] = Gr * s + Gi * c;
  }
  __syncthreads();
  fft256(re0, im0, twr, twi, lane, true);
  const float inv = 1.0f / 256.0f;
  float2* orow = A2 + (size_t)b * 65536 + (size_t)kx * 256;
  #pragma unroll
  for (int q = 0; q < 4; q++) {
    int yy = lane + q * 64;
    orow[yy] = make_float2(re0[yy] * inv, im0[yy] * inv);
  }
}

// --------- final: phase_x, inverse x-FFT, write real ----------
__global__ __launch_bounds__(64) void fft_final(const float2* __restrict__ A2t,
                                                const float* __restrict__ shift,
                                                float* __restrict__ out_imgs) {
  __shared__ float re[256], im[256], twr[128], twi[128];
  int lane = threadIdx.x;
  int b = blockIdx.x >> 8, y = blockIdx.x & 255;
  for (int t = lane; t < 128; t += 64) {
    float ang = -TWO_PI_F * (float)t / 256.0f;
    twr[t] = cosf(ang); twi[t] = sinf(ang);
  }
  const float2* row = A2t + (size_t)b * 65536 + (size_t)y * 256;
  float sx = shift[b * 2 + 0];
  #pragma unroll
  for (int q = 0; q < 4; q++) {
    int k = lane + q * 64;
    float2 v = row[k];
    float fk = (float)((k < 128) ? k : k - 256) / 256.0f;
    float th = -TWO_PI_F * fk * sx;
    float c = __cosf(th), s = __sinf(th);
    re[k] = v.x * c - v.y * s;
    im[k] = v.x * s + v.y * c;
  }
  __syncthreads();
  fft256(re, im, twr, twi, lane, true);
  const float inv = 1.0f / 256.0f;
  float* orow = out_imgs + (size_t)b * 65536 + (size_t)y * 256;
  #pragma unroll
  for (int q = 0; q < 4; q++) {
    int x = lane + q * 64;
    orow[x] = re[x] * inv;
  }
}

// ---------------- launch ----------------
extern "C" void kernel_launch(void* const* d_in, const int* in_sizes, int n_in,
                              void* d_out, int out_size, void* d_ws, size_t ws_size,
                              hipStream_t stream) {
  (void)in_sizes; (void)n_in; (void)out_size; (void)ws_size;
  const float* z       = (const float*)d_in[0];
  const float* orient  = (const float*)d_in[1];
  const float* shift   = (const float*)d_in[2];
  const float* mp      = (const float*)d_in[3];
  const float* W_in    = (const float*)d_in[4];
  const float* W_layers= (const float*)d_in[5];
  const float* W_out1  = (const float*)d_in[6];
  const float* W_out2  = (const float*)d_in[7];
  const float* amp     = (const float*)d_in[8];
  const float* ampvar  = (const float*)d_in[9];
  const float* Aarr    = (const float*)d_in[10];
  const float* Bparr   = (const float*)d_in[11];

  char* ws = (char*)d_ws;
  float*  splat   = (float*)ws;                       // 16 MB  [B][C][S][S]
  float2* ws1     = (float2*)(ws + 16777216);         // 32 MB  [B*C][256][256] complex
  float*  encpart = (float*)(ws + 50331648);          //  4 MB  [P][64]
  float2* A2      = (float2*)ws;                      // alias (splat dead after fft_rows)

  float* out      = (float*)d_out;
  float* out_imgs = out;                              // [B][S][S]
  float* out_fp   = out + (size_t)Bn * Sn * Sn;       // [B][P][3]
  float* out_disp = out_fp + (size_t)Bn * Pn * 3;     // [B][P][3]

  hipMemsetAsync(splat, 0, 16777216, stream);
  enc_kernel<<<Pn / 64, 64, 0, stream>>>(mp, W_in, encpart);
  mlp_splat_kernel<<<(Bn * Pn) / 256, 256, 0, stream>>>(
      encpart, z, W_in, W_layers, W_out1, W_out2, mp, orient, amp, ampvar,
      splat, out_fp, out_disp);
  fft_rows_fwd<<<Bn * Cn * Sn, 64, 0, stream>>>(splat, ws1);
  transpose_inplace<<<dim3(Bn * Cn, 36), 256, 0, stream>>>(ws1);
  fft_mid<<<Bn * Sn, 64, 0, stream>>>(ws1, A2, shift, Aarr, Bparr);
  transpose_inplace<<<dim3(Bn, 36), 256, 0, stream>>>(A2);
  fft_final<<<Bn * Sn, 64, 0, stream>>>(A2, shift, out_imgs);
}

// Round 3
// 489.391 us; speedup vs baseline: 1.4272x; 1.1743x over previous
//
#include <hip/hip_runtime.h>
#include <math.h>

static constexpr int Bn = 32, Pn = 16384, Cn = 2, Sn = 256;

#define TWO_PI_F 6.28318530717958647692f

typedef float v4f __attribute__((ext_vector_type(4)));
typedef short v8s __attribute__((ext_vector_type(8)));

__device__ __forceinline__ float elu_f(float x) {
  return x > 0.0f ? x : (__expf(x) - 1.0f);
}

__device__ __forceinline__ unsigned short f2bf(float x) {
  unsigned int u = __float_as_uint(x);
  u = u + 0x7FFFu + ((u >> 16) & 1u);   // round-to-nearest-even
  return (unsigned short)(u >> 16);
}

__device__ __forceinline__ void atomicAddF(float* p, float v) {
#if defined(__HIP_PLATFORM_AMD__)
  unsafeAtomicAdd(p, v);
#else
  atomicAdd(p, v);
#endif
}

// ---------------- 256-pt FFT in LDS, 64 threads -----------------
__device__ __forceinline__ void fft256(float* re, float* im,
                                       const float* twr, const float* twi,
                                       int lane, bool inverse) {
  #pragma unroll
  for (int q = 0; q < 4; q++) {
    int t = lane + q * 64;
    int r = (int)(__brev((unsigned)t) >> 24);
    if (t < r) {
      float a = re[t]; re[t] = re[r]; re[r] = a;
      float b = im[t]; im[t] = im[r]; im[r] = b;
    }
  }
  __syncthreads();
  #pragma unroll
  for (int s = 1; s <= 8; s++) {
    int half = 1 << (s - 1);
    #pragma unroll
    for (int q = 0; q < 2; q++) {
      int bf = lane + q * 64;
      int j = bf & (half - 1);
      int grp = bf >> (s - 1);
      int i0 = (grp << s) + j;
      int i1 = i0 + half;
      int tx = j << (8 - s);
      float wr = twr[tx];
      float wi = twi[tx];
      if (inverse) wi = -wi;
      float xr = re[i1], xi = im[i1];
      float tr = fmaf(xr, wr, -xi * wi);
      float ti = fmaf(xr, wi,  xi * wr);
      float ar = re[i0], ai = im[i0];
      re[i0] = ar + tr; im[i0] = ai + ti;
      re[i1] = ar - tr; im[i1] = ai - ti;
    }
    __syncthreads();
  }
}

// ---------------- enc precompute: encpart[p][64] = enc(p) @ W_in[0:60] ------
__global__ __launch_bounds__(64) void enc_kernel(const float* __restrict__ mp,
                                                 const float* __restrict__ W_in,
                                                 float* __restrict__ encpart) {
  __shared__ float ebuf[60][64];
  int tid = threadIdx.x;
  int p = blockIdx.x * 64 + tid;
  #pragma unroll
  for (int c = 0; c < 3; c++) {
    float pos = mp[p * 3 + c];
    #pragma unroll
    for (int i = 0; i < 10; i++) {
      float freq = powf(128.0f, (float)i / 9.0f);
      float ang = (TWO_PI_F * pos) * freq;
      ebuf[c * 20 + i][tid]      = sinf(ang);
      ebuf[c * 20 + 10 + i][tid] = cosf(ang);
    }
  }
  float h[64];
  #pragma unroll
  for (int j = 0; j < 64; j++) h[j] = 0.0f;
  for (int k = 0; k < 60; k++) {
    float ek = ebuf[k][tid];
    const float* wr = W_in + k * 64;
    #pragma unroll
    for (int j = 0; j < 64; j++) h[j] = fmaf(ek, wr[j], h[j]);
  }
  float* o = encpart + (size_t)p * 64;
  #pragma unroll
  for (int j = 0; j < 64; j++) o[j] = h[j];
}

// ---------------- prep: zpart[b][64] and weight B-fragments (bf16) ----------
// Wfrag[t2*8+i], t2 = ((L*4+n)*2+s)*64+lane, element = W_layers[L][k][c],
// k = s*32 + (lane>>4)*8 + i, c = n*16 + (lane&15)
__global__ __launch_bounds__(256) void prep_kernel(const float* __restrict__ z,
                                                   const float* __restrict__ W_in,
                                                   const float* __restrict__ W_layers,
                                                   float* __restrict__ zpart,
                                                   unsigned short* __restrict__ Wfrag) {
  int idx = blockIdx.x * 256 + threadIdx.x;     // 0..4095
  if (idx < 2048) {
    int b = idx >> 6, j = idx & 63;
    float s = 0.0f;
    #pragma unroll
    for (int k = 0; k < 10; k++) s = fmaf(z[b * 10 + k], W_in[(60 + k) * 64 + j], s);
    zpart[b * 64 + j] = s;
  } else {
    int t2 = idx - 2048;
    int L = t2 >> 9, n = (t2 >> 7) & 3, s = (t2 >> 6) & 1, lane = t2 & 63;
    #pragma unroll
    for (int i = 0; i < 8; i++) {
      int k = s * 32 + ((lane >> 4) * 8) + i;
      int c = n * 16 + (lane & 15);
      Wfrag[(size_t)t2 * 8 + i] = f2bf(W_layers[L * 4096 + k * 64 + c]);
    }
  }
}

// ---------------- MFMA MLP + project + splat ----------------
// 256 threads = 4 waves; each wave owns 64 rows (points) and a private
// 8 KB LDS tile (swizzled bf16 [64][64]); no __syncthreads needed.
__global__ __launch_bounds__(256, 2) void mlp_mfma_kernel(
    const float* __restrict__ encpart, const float* __restrict__ zpart,
    const unsigned short* __restrict__ Wfrag,
    const float* __restrict__ W_out1, const float* __restrict__ W_out2,
    const float* __restrict__ mp, const float* __restrict__ orient,
    const float* __restrict__ amp, const float* __restrict__ ampvar,
    float* __restrict__ splat, float* __restrict__ out_fp,
    float* __restrict__ out_disp) {
  __shared__ unsigned char ldsraw[32768];
  int tid = threadIdx.x;
  int wave = tid >> 6, lane = tid & 63;
  unsigned char* X = ldsraw + wave * 8192;
  int rowBase = blockIdx.x * 256 + wave * 64;
  int g = rowBase + lane;
  int b = g >> 14;          // g / Pn
  int p = g & (Pn - 1);

  // ---- stage X0 = bf16(encpart[p] + zpart[b]) into swizzled LDS (row = lane)
  {
    const v4f* ep = (const v4f*)(encpart + (size_t)p * 64);
    const v4f* zp = (const v4f*)(zpart + b * 64);
    int row = lane;
    #pragma unroll
    for (int q = 0; q < 8; q++) {
      v4f e0 = ep[2 * q],     z0 = zp[2 * q];
      v4f e1 = ep[2 * q + 1], z1 = zp[2 * q + 1];
      unsigned int w0 = (unsigned int)f2bf(e0.x + z0.x) | ((unsigned int)f2bf(e0.y + z0.y) << 16);
      unsigned int w1 = (unsigned int)f2bf(e0.z + z0.z) | ((unsigned int)f2bf(e0.w + z0.w) << 16);
      unsigned int w2 = (unsigned int)f2bf(e1.x + z1.x) | ((unsigned int)f2bf(e1.y + z1.y) << 16);
      unsigned int w3 = (unsigned int)f2bf(e1.z + z1.z) | ((unsigned int)f2bf(e1.w + z1.w) << 16);
      int off = (row * 128 + q * 16) ^ ((row & 7) << 4);
      *(uint4*)(X + off) = make_uint4(w0, w1, w2, w3);
    }
  }

  v4f acc[4][4];
  #pragma unroll
  for (int L = 0; L < 4; L++) {
    // B fragments: one coalesced 16B load per (n, s)
    v8s Bf[4][2];
    #pragma unroll
    for (int n = 0; n < 4; n++)
      #pragma unroll
      for (int s = 0; s < 2; s++)
        Bf[n][s] = *(const v8s*)(Wfrag + ((size_t)(((L * 4 + n) * 2 + s) * 64 + lane)) * 8);
    #pragma unroll
    for (int m = 0; m < 4; m++)
      #pragma unroll
      for (int n = 0; n < 4; n++)
        acc[m][n] = (v4f){0.f, 0.f, 0.f, 0.f};
    #pragma unroll
    for (int s = 0; s < 2; s++) {
      v8s Af[4];
      #pragma unroll
      for (int m = 0; m < 4; m++) {
        int row = m * 16 + (lane & 15);
        int off = (row * 128 + s * 64 + ((lane >> 4) * 16)) ^ ((row & 7) << 4);
        Af[m] = *(const v8s*)(X + off);
      }
      #pragma unroll
      for (int m = 0; m < 4; m++)
        #pragma unroll
        for (int n = 0; n < 4; n++)
          acc[m][n] = __builtin_amdgcn_mfma_f32_16x16x32_bf16(Af[m], Bf[n][s], acc[m][n], 0, 0, 0);
    }
    if (L < 3) {
      // elu + bf16, write back to swizzled X (D layout: col=lane&15, row=(lane>>4)*4+reg)
      #pragma unroll
      for (int m = 0; m < 4; m++)
        #pragma unroll
        for (int n = 0; n < 4; n++)
          #pragma unroll
          for (int r = 0; r < 4; r++) {
            float v = acc[m][n][r];
            v = v > 0.0f ? v : (__expf(v) - 1.0f);
            int row = m * 16 + ((lane >> 4) * 4) + r;
            int col = n * 16 + (lane & 15);
            int off = (row * 128 + col * 2) ^ ((row & 7) << 4);
            *(unsigned short*)(X + off) = f2bf(v);
          }
    }
  }

  // ---- head: fp32 via LDS round-trip, two column halves reuse the 8 KB tile
  float o0 = 0.f, o1 = 0.f, o2 = 0.f;
  #pragma unroll
  for (int half = 0; half < 2; half++) {
    #pragma unroll
    for (int nn = 0; nn < 2; nn++) {
      int n = 2 * half + nn;
      #pragma unroll
      for (int m = 0; m < 4; m++)
        #pragma unroll
        for (int r = 0; r < 4; r++) {
          int row = m * 16 + ((lane >> 4) * 4) + r;
          int colL = nn * 16 + (lane & 15);
          int off = (row * 128 + colL * 4) ^ ((row & 7) << 4);
          *(float*)(X + off) = acc[m][n][r];
        }
    }
    int rrow = lane;
    #pragma unroll
    for (int q = 0; q < 8; q++) {
      int off = (rrow * 128 + q * 16) ^ ((rrow & 7) << 4);
      v4f hv = *(const v4f*)(X + off);
      #pragma unroll
      for (int i = 0; i < 4; i++) {
        int c = half * 32 + q * 4 + i;
        float v = hv[i];
        v = v > 0.0f ? v : (__expf(v) - 1.0f);
        o0 = fmaf(v, W_out1[c * 3 + 0], o0);
        o1 = fmaf(v, W_out1[c * 3 + 1], o1);
        o2 = fmaf(v, W_out1[c * 3 + 2], o2);
      }
    }
  }
  o0 = elu_f(o0); o1 = elu_f(o1); o2 = elu_f(o2);
  float d0 = o0 * W_out2[0] + o1 * W_out2[3] + o2 * W_out2[6];
  float d1 = o0 * W_out2[1] + o1 * W_out2[4] + o2 * W_out2[7];
  float d2 = o0 * W_out2[2] + o1 * W_out2[5] + o2 * W_out2[8];

  float m0 = mp[p * 3 + 0], m1 = mp[p * 3 + 1], m2 = mp[p * 3 + 2];
  float f0 = m0 + d0, f1 = m1 + d1, f2 = m2 + d2;

  size_t ob = ((size_t)b * Pn + p) * 3;
  out_disp[ob + 0] = d0; out_disp[ob + 1] = d1; out_disp[ob + 2] = d2;
  out_fp[ob + 0] = f0; out_fp[ob + 1] = f1; out_fp[ob + 2] = f2;

  const float* R = orient + b * 9;
  float px = R[0] * f0 + R[1] * f1 + R[2] * f2;
  float py = R[3] * f0 + R[4] * f1 + R[5] * f2;

  float a0 = ampvar[p], a1 = ampvar[Pn + p];
  float mx = fmaxf(a0, a1);
  float e0 = __expf(a0 - mx), e1 = __expf(a1 - mx);
  float inv = 1.0f / (e0 + e1);
  float w0 = amp[p] * e0 * inv;
  float w1 = amp[Pn + p] * e1 * inv;

  float pxp = fminf(fmaxf((px + 0.5f) * 256.0f, 0.0f), 254.999f);
  float pyp = fminf(fmaxf((py + 0.5f) * 256.0f, 0.0f), 254.999f);
  int x0 = (int)floorf(pxp), y0 = (int)floorf(pyp);
  float fx = pxp - (float)x0, fy = pyp - (float)y0;
  int x1 = min(x0 + 1, 255), y1 = min(y0 + 1, 255);
  float w00 = (1.f - fx) * (1.f - fy), w10 = fx * (1.f - fy);
  float w01 = (1.f - fx) * fy,         w11 = fx * fy;
  float* img0 = splat + ((size_t)b * 2 + 0) * 65536;
  float* img1 = splat + ((size_t)b * 2 + 1) * 65536;
  int i00 = y0 * 256 + x0, i10 = y0 * 256 + x1;
  int i01 = y1 * 256 + x0, i11 = y1 * 256 + x1;
  atomicAddF(img0 + i00, w0 * w00); atomicAddF(img0 + i10, w0 * w10);
  atomicAddF(img0 + i01, w0 * w01); atomicAddF(img0 + i11, w0 * w11);
  atomicAddF(img1 + i00, w1 * w00); atomicAddF(img1 + i10, w1 * w10);
  atomicAddF(img1 + i01, w1 * w01); atomicAddF(img1 + i11, w1 * w11);
}

// ---------------- forward FFT along x, per (bc, y) row ----------------
__global__ __launch_bounds__(64) void fft_rows_fwd(const float* __restrict__ splat,
                                                   float2* __restrict__ ws1) {
  __shared__ float re[256], im[256], twr[128], twi[128];
  int lane = threadIdx.x;
  int bc = blockIdx.x >> 8, y = blockIdx.x & 255;
  for (int t = lane; t < 128; t += 64) {
    float ang = -TWO_PI_F * (float)t / 256.0f;
    twr[t] = cosf(ang); twi[t] = sinf(ang);
  }
  const float* row = splat + (size_t)bc * 65536 + (size_t)y * 256;
  #pragma unroll
  for (int q = 0; q < 4; q++) {
    int x = lane + q * 64;
    re[x] = row[x]; im[x] = 0.0f;
  }
  __syncthreads();
  fft256(re, im, twr, twi, lane, false);
  float2* orow = ws1 + (size_t)bc * 65536 + (size_t)y * 256;
  #pragma unroll
  for (int q = 0; q < 4; q++) {
    int k = lane + q * 64;
    orow[k] = make_float2(re[k], im[k]);
  }
}

// ---------------- in-place per-image 256x256 complex transpose ----------------
__global__ __launch_bounds__(256) void transpose_inplace(float2* __restrict__ data) {
  int img = blockIdx.x, task = blockIdx.y;
  int ti = 0, t = task;
  while (t >= 8 - ti) { t -= 8 - ti; ti++; }
  int tj = ti + t;
  __shared__ float2 ta[32][33];
  __shared__ float2 tb[32][33];
  int lx = threadIdx.x & 31, ly0 = threadIdx.x >> 5;
  float2* base = data + (size_t)img * 65536;
  if (ti == tj) {
    #pragma unroll
    for (int q = 0; q < 4; q++) {
      int ly = ly0 + q * 8;
      ta[ly][lx] = base[(size_t)(ti * 32 + ly) * 256 + ti * 32 + lx];
    }
    __syncthreads();
    #pragma unroll
    for (int q = 0; q < 4; q++) {
      int ly = ly0 + q * 8;
      base[(size_t)(ti * 32 + ly) * 256 + ti * 32 + lx] = ta[lx][ly];
    }
  } else {
    #pragma unroll
    for (int q = 0; q < 4; q++) {
      int ly = ly0 + q * 8;
      ta[ly][lx] = base[(size_t)(ti * 32 + ly) * 256 + tj * 32 + lx];
      tb[ly][lx] = base[(size_t)(tj * 32 + ly) * 256 + ti * 32 + lx];
    }
    __syncthreads();
    #pragma unroll
    for (int q = 0; q < 4; q++) {
      int ly = ly0 + q * 8;
      base[(size_t)(tj * 32 + ly) * 256 + ti * 32 + lx] = ta[lx][ly];
      base[(size_t)(ti * 32 + ly) * 256 + tj * 32 + lx] = tb[lx][ly];
    }
  }
}

// --------- middle: y-FFT both classes, filter-combine, phase_y, inverse y-FFT ----
__global__ __launch_bounds__(64) void fft_mid(const float2* __restrict__ ws1t,
                                              float2* __restrict__ A2,
                                              const float* __restrict__ shift,
                                              const float* __restrict__ Aarr,
                                              const float* __restrict__ Bparr) {
  __shared__ float re0[256], im0[256], re1[256], im1[256], twr[128], twi[128];
  int lane = threadIdx.x;
  int b = blockIdx.x >> 8, kx = blockIdx.x & 255;
  for (int t = lane; t < 128; t += 64) {
    float ang = -TWO_PI_F * (float)t / 256.0f;
    twr[t] = cosf(ang); twi[t] = sinf(ang);
  }
  const float2* r0 = ws1t + ((size_t)b * 2 + 0) * 65536 + (size_t)kx * 256;
  const float2* r1 = ws1t + ((size_t)b * 2 + 1) * 65536 + (size_t)kx * 256;
  #pragma unroll
  for (int q = 0; q < 4; q++) {
    int i = lane + q * 64;
    float2 v0 = r0[i], v1 = r1[i];
    re0[i] = v0.x; im0[i] = v0.y;
    re1[i] = v1.x; im1[i] = v1.y;
  }
  __syncthreads();
  fft256(re0, im0, twr, twi, lane, false);
  fft256(re1, im1, twr, twi, lane, false);

  float A0 = Aarr[0], A1 = Aarr[1], B0 = Bparr[0], B1 = Bparr[1];
  float sy = shift[b * 2 + 1];
  float rx = (kx <= 128) ? (float)kx : (float)(256 - kx);
  #pragma unroll
  for (int q = 0; q < 4; q++) {
    int ky = lane + q * 64;
    float ry = (ky <= 128) ? (float)ky : (float)(256 - ky);
    float R = sqrtf(rx * rx + ry * ry);
    float FF0 = A0 * A0 * __expf(-B0 * B0 * R);
    float FF1 = A1 * A1 * __expf(-B1 * B1 * R);
    float Gr = FF0 * re0[ky] + FF1 * re1[ky];
    float Gi = FF0 * im0[ky] + FF1 * im1[ky];
    float fk = (float)((ky < 128) ? ky : ky - 256) / 256.0f;
    float th = -TWO_PI_F * fk * sy;
    float c = __cosf(th), s = __sinf(th);
    re0[ky] = Gr * c - Gi * s;
    im0[ky] = Gr * s + Gi * c;
  }
  __syncthreads();
  fft256(re0, im0, twr, twi, lane, true);
  const float inv = 1.0f / 256.0f;
  float2* orow = A2 + (size_t)b * 65536 + (size_t)kx * 256;
  #pragma unroll
  for (int q = 0; q < 4; q++) {
    int yy = lane + q * 64;
    orow[yy] = make_float2(re0[yy] * inv, im0[yy] * inv);
  }
}

// --------- final: phase_x, inverse x-FFT, write real ----------
__global__ __launch_bounds__(64) void fft_final(const float2* __restrict__ A2t,
                                                const float* __restrict__ shift,
                                                float* __restrict__ out_imgs) {
  __shared__ float re[256], im[256], twr[128], twi[128];
  int lane = threadIdx.x;
  int b = blockIdx.x >> 8, y = blockIdx.x & 255;
  for (int t = lane; t < 128; t += 64) {
    float ang = -TWO_PI_F * (float)t / 256.0f;
    twr[t] = cosf(ang); twi[t] = sinf(ang);
  }
  const float2* row = A2t + (size_t)b * 65536 + (size_t)y * 256;
  float sx = shift[b * 2 + 0];
  #pragma unroll
  for (int q = 0; q < 4; q++) {
    int k = lane + q * 64;
    float2 v = row[k];
    float fk = (float)((k < 128) ? k : k - 256) / 256.0f;
    float th = -TWO_PI_F * fk * sx;
    float c = __cosf(th), s = __sinf(th);
    re[k] = v.x * c - v.y * s;
    im[k] = v.x * s + v.y * c;
  }
  __syncthreads();
  fft256(re, im, twr, twi, lane, true);
  const float inv = 1.0f / 256.0f;
  float* orow = out_imgs + (size_t)b * 65536 + (size_t)y * 256;
  #pragma unroll
  for (int q = 0; q < 4; q++) {
    int x = lane + q * 64;
    orow[x] = re[x] * inv;
  }
}

// ---------------- launch ----------------
extern "C" void kernel_launch(void* const* d_in, const int* in_sizes, int n_in,
                              void* d_out, int out_size, void* d_ws, size_t ws_size,
                              hipStream_t stream) {
  (void)in_sizes; (void)n_in; (void)out_size; (void)ws_size;
  const float* z       = (const float*)d_in[0];
  const float* orient  = (const float*)d_in[1];
  const float* shift   = (const float*)d_in[2];
  const float* mp      = (const float*)d_in[3];
  const float* W_in    = (const float*)d_in[4];
  const float* W_layers= (const float*)d_in[5];
  const float* W_out1  = (const float*)d_in[6];
  const float* W_out2  = (const float*)d_in[7];
  const float* amp     = (const float*)d_in[8];
  const float* ampvar  = (const float*)d_in[9];
  const float* Aarr    = (const float*)d_in[10];
  const float* Bparr   = (const float*)d_in[11];

  char* ws = (char*)d_ws;
  float*  splat   = (float*)ws;                        // 16 MB [B][C][S][S]
  float2* ws1     = (float2*)(ws + 16777216);          // 32 MB [B*C][256][256] complex
  float*  encpart = (float*)(ws + 50331648);           //  4 MB [P][64]
  float2* A2      = (float2*)ws;                       // alias (splat dead after fft_rows)
  // zpart + Wfrag live inside ws1's region during the MLP (ws1 written later)
  float*          zpart = (float*)(ws + 16777216);     // 8 KB [B][64]
  unsigned short* Wfrag = (unsigned short*)(ws + 16777216 + 8192); // 32 KB

  float* out      = (float*)d_out;
  float* out_imgs = out;                               // [B][S][S]
  float* out_fp   = out + (size_t)Bn * Sn * Sn;        // [B][P][3]
  float* out_disp = out_fp + (size_t)Bn * Pn * 3;      // [B][P][3]

  hipMemsetAsync(splat, 0, 16777216, stream);
  enc_kernel<<<Pn / 64, 64, 0, stream>>>(mp, W_in, encpart);
  prep_kernel<<<16, 256, 0, stream>>>(z, W_in, W_layers, zpart, Wfrag);
  mlp_mfma_kernel<<<(Bn * Pn) / 256, 256, 0, stream>>>(
      encpart, zpart, Wfrag, W_out1, W_out2, mp, orient, amp, ampvar,
      splat, out_fp, out_disp);
  fft_rows_fwd<<<Bn * Cn * Sn, 64, 0, stream>>>(splat, ws1);
  transpose_inplace<<<dim3(Bn * Cn, 36), 256, 0, stream>>>(ws1);
  fft_mid<<<Bn * Sn, 64, 0, stream>>>(ws1, A2, shift, Aarr, Bparr);
  transpose_inplace<<<dim3(Bn, 36), 256, 0, stream>>>(A2);
  fft_final<<<Bn * Sn, 64, 0, stream>>>(A2, shift, out_imgs);
}

// Round 4
// 335.856 us; speedup vs baseline: 2.0796x; 1.4571x over previous
//
#include <hip/hip_runtime.h>
#include <math.h>

static constexpr int Bn = 32, Pn = 16384, Cn = 2, Sn = 256;

#define TWO_PI_F 6.28318530717958647692f

typedef float v4f __attribute__((ext_vector_type(4)));
typedef short v8s __attribute__((ext_vector_type(8)));

__device__ __forceinline__ float elu_f(float x) {
  return x > 0.0f ? x : (__expf(x) - 1.0f);
}

__device__ __forceinline__ unsigned short f2bf(float x) {
  unsigned int u = __float_as_uint(x);
  u = u + 0x7FFFu + ((u >> 16) & 1u);
  return (unsigned short)(u >> 16);
}

__device__ __forceinline__ int cvt_pk_bf16(float lo, float hi) {
  int r;
  asm("v_cvt_pk_bf16_f32 %0, %1, %2" : "=v"(r) : "v"(lo), "v"(hi));
  return r;
}

__device__ __forceinline__ void atomicAddF(float* p, float v) {
#if defined(__HIP_PLATFORM_AMD__)
  unsafeAtomicAdd(p, v);
#else
  atomicAdd(p, v);
#endif
}

// ---------------- 256-pt FFT in LDS, 64 threads -----------------
__device__ __forceinline__ void fft256(float* re, float* im,
                                       const float* twr, const float* twi,
                                       int lane, bool inverse) {
  #pragma unroll
  for (int q = 0; q < 4; q++) {
    int t = lane + q * 64;
    int r = (int)(__brev((unsigned)t) >> 24);
    if (t < r) {
      float a = re[t]; re[t] = re[r]; re[r] = a;
      float b = im[t]; im[t] = im[r]; im[r] = b;
    }
  }
  __syncthreads();
  #pragma unroll
  for (int s = 1; s <= 8; s++) {
    int half = 1 << (s - 1);
    #pragma unroll
    for (int q = 0; q < 2; q++) {
      int bf = lane + q * 64;
      int j = bf & (half - 1);
      int grp = bf >> (s - 1);
      int i0 = (grp << s) + j;
      int i1 = i0 + half;
      int tx = j << (8 - s);
      float wr = twr[tx];
      float wi = twi[tx];
      if (inverse) wi = -wi;
      float xr = re[i1], xi = im[i1];
      float tr = fmaf(xr, wr, -xi * wi);
      float ti = fmaf(xr, wi,  xi * wr);
      float ar = re[i0], ai = im[i0];
      re[i0] = ar + tr; im[i0] = ai + ti;
      re[i1] = ar - tr; im[i1] = ai - ti;
    }
    __syncthreads();
  }
}

// ---------------- enc precompute: encpart[p][64] = enc(p) @ W_in[0:60] ------
__global__ __launch_bounds__(64) void enc_kernel(const float* __restrict__ mp,
                                                 const float* __restrict__ W_in,
                                                 float* __restrict__ encpart) {
  __shared__ float ebuf[60][64];
  int tid = threadIdx.x;
  int p = blockIdx.x * 64 + tid;
  #pragma unroll
  for (int c = 0; c < 3; c++) {
    float pos = mp[p * 3 + c];
    #pragma unroll
    for (int i = 0; i < 10; i++) {
      float freq = powf(128.0f, (float)i / 9.0f);
      float ang = (TWO_PI_F * pos) * freq;
      ebuf[c * 20 + i][tid]      = sinf(ang);
      ebuf[c * 20 + 10 + i][tid] = cosf(ang);
    }
  }
  float h[64];
  #pragma unroll
  for (int j = 0; j < 64; j++) h[j] = 0.0f;
  for (int k = 0; k < 60; k++) {
    float ek = ebuf[k][tid];
    const float* wr = W_in + k * 64;
    #pragma unroll
    for (int j = 0; j < 64; j++) h[j] = fmaf(ek, wr[j], h[j]);
  }
  float* o = encpart + (size_t)p * 64;
  #pragma unroll
  for (int j = 0; j < 64; j++) o[j] = h[j];
}

// ---------------- prep: zpart[b][64] and W^T A-fragments (bf16) ----------
// Wfrag[t2*8+i], t2 = ((L*4+m)*2+s)*64+lane, element = W_layers[L][k][j],
// k = s*32 + (lane>>4)*8 + i, j = m*16 + (lane&15)
__global__ __launch_bounds__(256) void prep_kernel(const float* __restrict__ z,
                                                   const float* __restrict__ W_in,
                                                   const float* __restrict__ W_layers,
                                                   float* __restrict__ zpart,
                                                   unsigned short* __restrict__ Wfrag) {
  int idx = blockIdx.x * 256 + threadIdx.x;     // 0..4095
  if (idx < 2048) {
    int b = idx >> 6, j = idx & 63;
    float s = 0.0f;
    #pragma unroll
    for (int k = 0; k < 10; k++) s = fmaf(z[b * 10 + k], W_in[(60 + k) * 64 + j], s);
    zpart[b * 64 + j] = s;
  } else {
    int t2 = idx - 2048;
    int L = t2 >> 9, m = (t2 >> 7) & 3, s = (t2 >> 6) & 1, lane = t2 & 63;
    #pragma unroll
    for (int i = 0; i < 8; i++) {
      int k = s * 32 + ((lane >> 4) * 8) + i;
      int j = m * 16 + (lane & 15);
      Wfrag[(size_t)t2 * 8 + i] = f2bf(W_layers[L * 4096 + k * 64 + j]);
    }
  }
}

// ---------------- all-register MFMA MLP + project + splat ----------------
// 1 wave = 16 points (H^T formulation). No LDS, no barriers.
// acc[m][r] (lane: g=lane>>4, p=lane&15) = H[point p][j = m*16 + g*4 + r].
__global__ __launch_bounds__(256) void mlp_mfma16_kernel(
    const float* __restrict__ encpart, const float* __restrict__ zpart,
    const unsigned short* __restrict__ Wfrag,
    const float* __restrict__ W_out1, const float* __restrict__ W_out2,
    const float* __restrict__ mp, const float* __restrict__ orient,
    const float* __restrict__ amp, const float* __restrict__ ampvar,
    float* __restrict__ splat, float* __restrict__ out_fp,
    float* __restrict__ out_disp) {
  int tid = threadIdx.x;
  int lane = tid & 63;
  int wid = blockIdx.x * 4 + (tid >> 6);          // 0..32767
  int b = __builtin_amdgcn_readfirstlane(wid >> 10);
  int pbase = (wid & 1023) * 16;
  int g = lane >> 4;
  int p = pbase + (lane & 15);

  union U4 { int u[4]; v8s v; };

  // ---- layer-0 B fragments: X0^T[k][p], k = s*32 + g*8 + i
  v8s Bf[2];
  #pragma unroll
  for (int s = 0; s < 2; s++) {
    int k0 = s * 32 + g * 8;
    const float4* e4 = (const float4*)(encpart + (size_t)p * 64 + k0);
    const float4* z4 = (const float4*)(zpart + b * 64 + k0);
    float4 e0 = e4[0], e1 = e4[1];
    float4 z0 = z4[0], z1 = z4[1];
    U4 u;
    u.u[0] = cvt_pk_bf16(e0.x + z0.x, e0.y + z0.y);
    u.u[1] = cvt_pk_bf16(e0.z + z0.z, e0.w + z0.w);
    u.u[2] = cvt_pk_bf16(e1.x + z1.x, e1.y + z1.y);
    u.u[3] = cvt_pk_bf16(e1.z + z1.z, e1.w + z1.w);
    Bf[s] = u.v;
  }

  // permute source lanes (bpermute index = srcLane*4)
  int srcA = ((((lane >> 4) & 1) * 32) + (lane & 15)) << 2;
  int srcB = srcA + 64;
  bool hi = (lane >> 5) & 1;

  const v8s* WfragV = (const v8s*)Wfrag;
  v4f acc[4];

  #pragma unroll 1
  for (int L = 0; L < 4; L++) {
    // W^T A-fragments: coalesced 16B/lane, L1/L2-resident
    v8s Af[4][2];
    #pragma unroll
    for (int m = 0; m < 4; m++)
      #pragma unroll
      for (int s = 0; s < 2; s++)
        Af[m][s] = WfragV[(size_t)(((L * 4 + m) * 2 + s) * 64) + lane];

    #pragma unroll
    for (int m = 0; m < 4; m++) acc[m] = (v4f){0.f, 0.f, 0.f, 0.f};
    #pragma unroll
    for (int s = 0; s < 2; s++)
      #pragma unroll
      for (int m = 0; m < 4; m++)
        acc[m] = __builtin_amdgcn_mfma_f32_16x16x32_bf16(Af[m][s], Bf[s], acc[m], 0, 0, 0);

    // ELU on all 16 outputs
    #pragma unroll
    for (int m = 0; m < 4; m++)
      #pragma unroll
      for (int r = 0; r < 4; r++)
        acc[m][r] = elu_f(acc[m][r]);

    if (L < 3) {
      // pack to bf16 pairs: pk[m][0]=(r0,r1), pk[m][1]=(r2,r3)
      int pk[4][2];
      #pragma unroll
      for (int m = 0; m < 4; m++) {
        pk[m][0] = cvt_pk_bf16(acc[m][0], acc[m][1]);
        pk[m][1] = cvt_pk_bf16(acc[m][2], acc[m][3]);
      }
      // regroup D -> next-layer B frags: fixed lane-group gather
      #pragma unroll
      for (int s = 0; s < 2; s++) {
        int t00 = __builtin_amdgcn_ds_bpermute(srcA, pk[2 * s][0]);
        int t01 = __builtin_amdgcn_ds_bpermute(srcA, pk[2 * s + 1][0]);
        int t10 = __builtin_amdgcn_ds_bpermute(srcA, pk[2 * s][1]);
        int t11 = __builtin_amdgcn_ds_bpermute(srcA, pk[2 * s + 1][1]);
        int t20 = __builtin_amdgcn_ds_bpermute(srcB, pk[2 * s][0]);
        int t21 = __builtin_amdgcn_ds_bpermute(srcB, pk[2 * s + 1][0]);
        int t30 = __builtin_amdgcn_ds_bpermute(srcB, pk[2 * s][1]);
        int t31 = __builtin_amdgcn_ds_bpermute(srcB, pk[2 * s + 1][1]);
        U4 u;
        u.u[0] = hi ? t01 : t00;
        u.u[1] = hi ? t11 : t10;
        u.u[2] = hi ? t21 : t20;
        u.u[3] = hi ? t31 : t30;
        Bf[s] = u.v;
      }
    }
  }

  // ---- head: per-lane partials over its 16 j's, then cross-group reduce
  float o0 = 0.f, o1 = 0.f, o2 = 0.f;
  #pragma unroll
  for (int m = 0; m < 4; m++) {
    int jb = m * 16 + g * 4;
    const float4* w4 = (const float4*)(W_out1 + jb * 3);
    float4 wa = w4[0], wb = w4[1], wc = w4[2];
    o0 += acc[m][0] * wa.x + acc[m][1] * wa.w + acc[m][2] * wb.z + acc[m][3] * wc.y;
    o1 += acc[m][0] * wa.y + acc[m][1] * wb.x + acc[m][2] * wb.w + acc[m][3] * wc.z;
    o2 += acc[m][0] * wa.z + acc[m][1] * wb.y + acc[m][2] * wc.x + acc[m][3] * wc.w;
  }
  o0 += __shfl_xor(o0, 16, 64); o0 += __shfl_xor(o0, 32, 64);
  o1 += __shfl_xor(o1, 16, 64); o1 += __shfl_xor(o1, 32, 64);
  o2 += __shfl_xor(o2, 16, 64); o2 += __shfl_xor(o2, 32, 64);

  o0 = elu_f(o0); o1 = elu_f(o1); o2 = elu_f(o2);
  float d0 = o0 * W_out2[0] + o1 * W_out2[3] + o2 * W_out2[6];
  float d1 = o0 * W_out2[1] + o1 * W_out2[4] + o2 * W_out2[7];
  float d2 = o0 * W_out2[2] + o1 * W_out2[5] + o2 * W_out2[8];

  float m0 = mp[p * 3 + 0], m1 = mp[p * 3 + 1], m2 = mp[p * 3 + 2];
  float f0 = m0 + d0, f1 = m1 + d1, f2 = m2 + d2;

  size_t ob = ((size_t)b * Pn + p) * 3;
  if (g == 1) { out_disp[ob + 0] = d0; out_disp[ob + 1] = d1; out_disp[ob + 2] = d2; }
  if (g == 2) { out_fp[ob + 0] = f0; out_fp[ob + 1] = f1; out_fp[ob + 2] = f2; }

  const float* R = orient + b * 9;
  float px = R[0] * f0 + R[1] * f1 + R[2] * f2;
  float py = R[3] * f0 + R[4] * f1 + R[5] * f2;

  float a0 = ampvar[p], a1 = ampvar[Pn + p];
  float mx = fmaxf(a0, a1);
  float e0 = __expf(a0 - mx), e1 = __expf(a1 - mx);
  float inv = 1.0f / (e0 + e1);
  float w0 = amp[p] * e0 * inv;
  float w1 = amp[Pn + p] * e1 * inv;

  // bilinear splat: lane-group g handles neighbor g (all 64 lanes active)
  float pxp = fminf(fmaxf((px + 0.5f) * 256.0f, 0.0f), 254.999f);
  float pyp = fminf(fmaxf((py + 0.5f) * 256.0f, 0.0f), 254.999f);
  int x0 = (int)floorf(pxp), y0 = (int)floorf(pyp);
  float fx = pxp - (float)x0, fy = pyp - (float)y0;
  int x1 = min(x0 + 1, 255), y1 = min(y0 + 1, 255);
  int xt = (g & 1) ? x1 : x0;
  int yt = (g & 2) ? y1 : y0;
  float wx = (g & 1) ? fx : (1.f - fx);
  float wy = (g & 2) ? fy : (1.f - fy);
  float w = wx * wy;
  int idx = yt * 256 + xt;
  float* img0 = splat + ((size_t)b * 2 + 0) * 65536;
  float* img1 = splat + ((size_t)b * 2 + 1) * 65536;
  atomicAddF(img0 + idx, w0 * w);
  atomicAddF(img1 + idx, w1 * w);
}

// ---------------- forward FFT along x, per (bc, y) row ----------------
__global__ __launch_bounds__(64) void fft_rows_fwd(const float* __restrict__ splat,
                                                   float2* __restrict__ ws1) {
  __shared__ float re[256], im[256], twr[128], twi[128];
  int lane = threadIdx.x;
  int bc = blockIdx.x >> 8, y = blockIdx.x & 255;
  for (int t = lane; t < 128; t += 64) {
    float ang = -TWO_PI_F * (float)t / 256.0f;
    twr[t] = cosf(ang); twi[t] = sinf(ang);
  }
  const float* row = splat + (size_t)bc * 65536 + (size_t)y * 256;
  #pragma unroll
  for (int q = 0; q < 4; q++) {
    int x = lane + q * 64;
    re[x] = row[x]; im[x] = 0.0f;
  }
  __syncthreads();
  fft256(re, im, twr, twi, lane, false);
  float2* orow = ws1 + (size_t)bc * 65536 + (size_t)y * 256;
  #pragma unroll
  for (int q = 0; q < 4; q++) {
    int k = lane + q * 64;
    orow[k] = make_float2(re[k], im[k]);
  }
}

// ---------------- in-place per-image 256x256 complex transpose ----------------
__global__ __launch_bounds__(256) void transpose_inplace(float2* __restrict__ data) {
  int img = blockIdx.x, task = blockIdx.y;
  int ti = 0, t = task;
  while (t >= 8 - ti) { t -= 8 - ti; ti++; }
  int tj = ti + t;
  __shared__ float2 ta[32][33];
  __shared__ float2 tb[32][33];
  int lx = threadIdx.x & 31, ly0 = threadIdx.x >> 5;
  float2* base = data + (size_t)img * 65536;
  if (ti == tj) {
    #pragma unroll
    for (int q = 0; q < 4; q++) {
      int ly = ly0 + q * 8;
      ta[ly][lx] = base[(size_t)(ti * 32 + ly) * 256 + ti * 32 + lx];
    }
    __syncthreads();
    #pragma unroll
    for (int q = 0; q < 4; q++) {
      int ly = ly0 + q * 8;
      base[(size_t)(ti * 32 + ly) * 256 + ti * 32 + lx] = ta[lx][ly];
    }
  } else {
    #pragma unroll
    for (int q = 0; q < 4; q++) {
      int ly = ly0 + q * 8;
      ta[ly][lx] = base[(size_t)(ti * 32 + ly) * 256 + tj * 32 + lx];
      tb[ly][lx] = base[(size_t)(tj * 32 + ly) * 256 + ti * 32 + lx];
    }
    __syncthreads();
    #pragma unroll
    for (int q = 0; q < 4; q++) {
      int ly = ly0 + q * 8;
      base[(size_t)(tj * 32 + ly) * 256 + ti * 32 + lx] = ta[lx][ly];
      base[(size_t)(ti * 32 + ly) * 256 + tj * 32 + lx] = tb[lx][ly];
    }
  }
}

// --------- middle: y-FFT both classes, filter-combine, phase_y, inverse y-FFT ----
__global__ __launch_bounds__(64) void fft_mid(const float2* __restrict__ ws1t,
                                              float2* __restrict__ A2,
                                              const float* __restrict__ shift,
                                              const float* __restrict__ Aarr,
                                              const float* __restrict__ Bparr) {
  __shared__ float re0[256], im0[256], re1[256], im1[256], twr[128], twi[128];
  int lane = threadIdx.x;
  int b = blockIdx.x >> 8, kx = blockIdx.x & 255;
  for (int t = lane; t < 128; t += 64) {
    float ang = -TWO_PI_F * (float)t / 256.0f;
    twr[t] = cosf(ang); twi[t] = sinf(ang);
  }
  const float2* r0 = ws1t + ((size_t)b * 2 + 0) * 65536 + (size_t)kx * 256;
  const float2* r1 = ws1t + ((size_t)b * 2 + 1) * 65536 + (size_t)kx * 256;
  #pragma unroll
  for (int q = 0; q < 4; q++) {
    int i = lane + q * 64;
    float2 v0 = r0[i], v1 = r1[i];
    re0[i] = v0.x; im0[i] = v0.y;
    re1[i] = v1.x; im1[i] = v1.y;
  }
  __syncthreads();
  fft256(re0, im0, twr, twi, lane, false);
  fft256(re1, im1, twr, twi, lane, false);

  float A0 = Aarr[0], A1 = Aarr[1], B0 = Bparr[0], B1 = Bparr[1];
  float sy = shift[b * 2 + 1];
  float rx = (kx <= 128) ? (float)kx : (float)(256 - kx);
  #pragma unroll
  for (int q = 0; q < 4; q++) {
    int ky = lane + q * 64;
    float ry = (ky <= 128) ? (float)ky : (float)(256 - ky);
    float R = sqrtf(rx * rx + ry * ry);
    float FF0 = A0 * A0 * __expf(-B0 * B0 * R);
    float FF1 = A1 * A1 * __expf(-B1 * B1 * R);
    float Gr = FF0 * re0[ky] + FF1 * re1[ky];
    float Gi = FF0 * im0[ky] + FF1 * im1[ky];
    float fk = (float)((ky < 128) ? ky : ky - 256) / 256.0f;
    float th = -TWO_PI_F * fk * sy;
    float c = __cosf(th), s = __sinf(th);
    re0[ky] = Gr * c - Gi * s;
    im0[ky] = Gr * s + Gi * c;
  }
  __syncthreads();
  fft256(re0, im0, twr, twi, lane, true);
  const float inv = 1.0f / 256.0f;
  float2* orow = A2 + (size_t)b * 65536 + (size_t)kx * 256;
  #pragma unroll
  for (int q = 0; q < 4; q++) {
    int yy = lane + q * 64;
    orow[yy] = make_float2(re0[yy] * inv, im0[yy] * inv);
  }
}

// --------- final: phase_x, inverse x-FFT, write real ----------
__global__ __launch_bounds__(64) void fft_final(const float2* __restrict__ A2t,
                                                const float* __restrict__ shift,
                                                float* __restrict__ out_imgs) {
  __shared__ float re[256], im[256], twr[128], twi[128];
  int lane = threadIdx.x;
  int b = blockIdx.x >> 8, y = blockIdx.x & 255;
  for (int t = lane; t < 128; t += 64) {
    float ang = -TWO_PI_F * (float)t / 256.0f;
    twr[t] = cosf(ang); twi[t] = sinf(ang);
  }
  const float2* row = A2t + (size_t)b * 65536 + (size_t)y * 256;
  float sx = shift[b * 2 + 0];
  #pragma unroll
  for (int q = 0; q < 4; q++) {
    int k = lane + q * 64;
    float2 v = row[k];
    float fk = (float)((k < 128) ? k : k - 256) / 256.0f;
    float th = -TWO_PI_F * fk * sx;
    float c = __cosf(th), s = __sinf(th);
    re[k] = v.x * c - v.y * s;
    im[k] = v.x * s + v.y * c;
  }
  __syncthreads();
  fft256(re, im, twr, twi, lane, true);
  const float inv = 1.0f / 256.0f;
  float* orow = out_imgs + (size_t)b * 65536 + (size_t)y * 256;
  #pragma unroll
  for (int q = 0; q < 4; q++) {
    int x = lane + q * 64;
    orow[x] = re[x] * inv;
  }
}

// ---------------- launch ----------------
extern "C" void kernel_launch(void* const* d_in, const int* in_sizes, int n_in,
                              void* d_out, int out_size, void* d_ws, size_t ws_size,
                              hipStream_t stream) {
  (void)in_sizes; (void)n_in; (void)out_size; (void)ws_size;
  const float* z       = (const float*)d_in[0];
  const float* orient  = (const float*)d_in[1];
  const float* shift   = (const float*)d_in[2];
  const float* mp      = (const float*)d_in[3];
  const float* W_in    = (const float*)d_in[4];
  const float* W_layers= (const float*)d_in[5];
  const float* W_out1  = (const float*)d_in[6];
  const float* W_out2  = (const float*)d_in[7];
  const float* amp     = (const float*)d_in[8];
  const float* ampvar  = (const float*)d_in[9];
  const float* Aarr    = (const float*)d_in[10];
  const float* Bparr   = (const float*)d_in[11];

  char* ws = (char*)d_ws;
  float*  splat   = (float*)ws;                        // 16 MB [B][C][S][S]
  float2* ws1     = (float2*)(ws + 16777216);          // 32 MB [B*C][256][256] complex
  float*  encpart = (float*)(ws + 50331648);           //  4 MB [P][64]
  float2* A2      = (float2*)ws;                       // alias (splat dead after fft_rows)
  float*          zpart = (float*)(ws + 16777216);     // 8 KB [B][64]
  unsigned short* Wfrag = (unsigned short*)(ws + 16777216 + 8192); // 32 KB

  float* out      = (float*)d_out;
  float* out_imgs = out;                               // [B][S][S]
  float* out_fp   = out + (size_t)Bn * Sn * Sn;        // [B][P][3]
  float* out_disp = out_fp + (size_t)Bn * Pn * 3;      // [B][P][3]

  hipMemsetAsync(splat, 0, 16777216, stream);
  enc_kernel<<<Pn / 64, 64, 0, stream>>>(mp, W_in, encpart);
  prep_kernel<<<16, 256, 0, stream>>>(z, W_in, W_layers, zpart, Wfrag);
  mlp_mfma16_kernel<<<(Bn * Pn / 16) / 4, 256, 0, stream>>>(
      encpart, zpart, Wfrag, W_out1, W_out2, mp, orient, amp, ampvar,
      splat, out_fp, out_disp);
  fft_rows_fwd<<<Bn * Cn * Sn, 64, 0, stream>>>(splat, ws1);
  transpose_inplace<<<dim3(Bn * Cn, 36), 256, 0, stream>>>(ws1);
  fft_mid<<<Bn * Sn, 64, 0, stream>>>(ws1, A2, shift, Aarr, Bparr);
  transpose_inplace<<<dim3(Bn, 36), 256, 0, stream>>>(A2);
  fft_final<<<Bn * Sn, 64, 0, stream>>>(A2, shift, out_imgs);
}

// Round 5
// 304.723 us; speedup vs baseline: 2.2921x; 1.1022x over previous
//
#include <hip/hip_runtime.h>
#include <math.h>

static constexpr int Bn = 32, Pn = 16384, Cn = 2, Sn = 256;

#define TWO_PI_F 6.28318530717958647692f

typedef float v4f __attribute__((ext_vector_type(4)));
typedef short v8s __attribute__((ext_vector_type(8)));

__device__ __forceinline__ float elu_f(float x) {
  return x > 0.0f ? x : (__expf(x) - 1.0f);
}

__device__ __forceinline__ unsigned short f2bf(float x) {
  unsigned int u = __float_as_uint(x);
  u = u + 0x7FFFu + ((u >> 16) & 1u);
  return (unsigned short)(u >> 16);
}

__device__ __forceinline__ int cvt_pk_bf16(float lo, float hi) {
  int r;
  asm("v_cvt_pk_bf16_f32 %0, %1, %2" : "=v"(r) : "v"(lo), "v"(hi));
  return r;
}

// ---------------- 256-pt FFT in LDS, 64 threads -----------------
__device__ __forceinline__ void fft256(float* re, float* im,
                                       const float* twr, const float* twi,
                                       int lane, bool inverse) {
  #pragma unroll
  for (int q = 0; q < 4; q++) {
    int t = lane + q * 64;
    int r = (int)(__brev((unsigned)t) >> 24);
    if (t < r) {
      float a = re[t]; re[t] = re[r]; re[r] = a;
      float b = im[t]; im[t] = im[r]; im[r] = b;
    }
  }
  __syncthreads();
  #pragma unroll
  for (int s = 1; s <= 8; s++) {
    int half = 1 << (s - 1);
    #pragma unroll
    for (int q = 0; q < 2; q++) {
      int bf = lane + q * 64;
      int j = bf & (half - 1);
      int grp = bf >> (s - 1);
      int i0 = (grp << s) + j;
      int i1 = i0 + half;
      int tx = j << (8 - s);
      float wr = twr[tx];
      float wi = twi[tx];
      if (inverse) wi = -wi;
      float xr = re[i1], xi = im[i1];
      float tr = fmaf(xr, wr, -xi * wi);
      float ti = fmaf(xr, wi,  xi * wr);
      float ar = re[i0], ai = im[i0];
      re[i0] = ar + tr; im[i0] = ai + ti;
      re[i1] = ar - tr; im[i1] = ai - ti;
    }
    __syncthreads();
  }
}

// ---------------- enc precompute: encpart[p][64] = enc(p) @ W_in[0:60] ------
__global__ __launch_bounds__(64) void enc_kernel(const float* __restrict__ mp,
                                                 const float* __restrict__ W_in,
                                                 float* __restrict__ encpart) {
  __shared__ float ebuf[60][64];
  int tid = threadIdx.x;
  int p = blockIdx.x * 64 + tid;
  #pragma unroll
  for (int c = 0; c < 3; c++) {
    float pos = mp[p * 3 + c];
    #pragma unroll
    for (int i = 0; i < 10; i++) {
      float freq = powf(128.0f, (float)i / 9.0f);
      float ang = (TWO_PI_F * pos) * freq;
      ebuf[c * 20 + i][tid]      = sinf(ang);
      ebuf[c * 20 + 10 + i][tid] = cosf(ang);
    }
  }
  float h[64];
  #pragma unroll
  for (int j = 0; j < 64; j++) h[j] = 0.0f;
  for (int k = 0; k < 60; k++) {
    float ek = ebuf[k][tid];
    const float* wr = W_in + k * 64;
    #pragma unroll
    for (int j = 0; j < 64; j++) h[j] = fmaf(ek, wr[j], h[j]);
  }
  float* o = encpart + (size_t)p * 64;
  #pragma unroll
  for (int j = 0; j < 64; j++) o[j] = h[j];
}

// ---------------- prep: zpart[b][64] and W^T A-fragments (bf16) ----------
__global__ __launch_bounds__(256) void prep_kernel(const float* __restrict__ z,
                                                   const float* __restrict__ W_in,
                                                   const float* __restrict__ W_layers,
                                                   float* __restrict__ zpart,
                                                   unsigned short* __restrict__ Wfrag) {
  int idx = blockIdx.x * 256 + threadIdx.x;     // 0..4095
  if (idx < 2048) {
    int b = idx >> 6, j = idx & 63;
    float s = 0.0f;
    #pragma unroll
    for (int k = 0; k < 10; k++) s = fmaf(z[b * 10 + k], W_in[(60 + k) * 64 + j], s);
    zpart[b * 64 + j] = s;
  } else {
    int t2 = idx - 2048;
    int L = t2 >> 9, m = (t2 >> 7) & 3, s = (t2 >> 6) & 1, lane = t2 & 63;
    #pragma unroll
    for (int i = 0; i < 8; i++) {
      int k = s * 32 + ((lane >> 4) * 8) + i;
      int j = m * 16 + (lane & 15);
      Wfrag[(size_t)t2 * 8 + i] = f2bf(W_layers[L * 4096 + k * 64 + j]);
    }
  }
}

// ---------------- all-register MFMA MLP + project -> records ----------------
__global__ __launch_bounds__(256) void mlp_mfma16_kernel(
    const float* __restrict__ encpart, const float* __restrict__ zpart,
    const unsigned short* __restrict__ Wfrag,
    const float* __restrict__ W_out1, const float* __restrict__ W_out2,
    const float* __restrict__ mp, const float* __restrict__ orient,
    const float* __restrict__ amp, const float* __restrict__ ampvar,
    float4* __restrict__ rec, float* __restrict__ out_fp,
    float* __restrict__ out_disp) {
  int tid = threadIdx.x;
  int lane = tid & 63;
  int wid = blockIdx.x * 4 + (tid >> 6);          // 0..32767
  int b = __builtin_amdgcn_readfirstlane(wid >> 10);
  int pbase = (wid & 1023) * 16;
  int g = lane >> 4;
  int p = pbase + (lane & 15);

  union U4 { int u[4]; v8s v; };

  // ---- layer-0 B fragments: X0^T[k][p], k = s*32 + g*8 + i
  v8s Bf[2];
  #pragma unroll
  for (int s = 0; s < 2; s++) {
    int k0 = s * 32 + g * 8;
    const float4* e4 = (const float4*)(encpart + (size_t)p * 64 + k0);
    const float4* z4 = (const float4*)(zpart + b * 64 + k0);
    float4 e0 = e4[0], e1 = e4[1];
    float4 z0 = z4[0], z1 = z4[1];
    U4 u;
    u.u[0] = cvt_pk_bf16(e0.x + z0.x, e0.y + z0.y);
    u.u[1] = cvt_pk_bf16(e0.z + z0.z, e0.w + z0.w);
    u.u[2] = cvt_pk_bf16(e1.x + z1.x, e1.y + z1.y);
    u.u[3] = cvt_pk_bf16(e1.z + z1.z, e1.w + z1.w);
    Bf[s] = u.v;
  }

  int srcA = ((((lane >> 4) & 1) * 32) + (lane & 15)) << 2;
  int srcB = srcA + 64;
  bool hi = (lane >> 5) & 1;

  const v8s* WfragV = (const v8s*)Wfrag;
  v4f acc[4];

  #pragma unroll 1
  for (int L = 0; L < 4; L++) {
    v8s Af[4][2];
    #pragma unroll
    for (int m = 0; m < 4; m++)
      #pragma unroll
      for (int s = 0; s < 2; s++)
        Af[m][s] = WfragV[(size_t)(((L * 4 + m) * 2 + s) * 64) + lane];

    #pragma unroll
    for (int m = 0; m < 4; m++) acc[m] = (v4f){0.f, 0.f, 0.f, 0.f};
    #pragma unroll
    for (int s = 0; s < 2; s++)
      #pragma unroll
      for (int m = 0; m < 4; m++)
        acc[m] = __builtin_amdgcn_mfma_f32_16x16x32_bf16(Af[m][s], Bf[s], acc[m], 0, 0, 0);

    #pragma unroll
    for (int m = 0; m < 4; m++)
      #pragma unroll
      for (int r = 0; r < 4; r++)
        acc[m][r] = elu_f(acc[m][r]);

    if (L < 3) {
      int pk[4][2];
      #pragma unroll
      for (int m = 0; m < 4; m++) {
        pk[m][0] = cvt_pk_bf16(acc[m][0], acc[m][1]);
        pk[m][1] = cvt_pk_bf16(acc[m][2], acc[m][3]);
      }
      #pragma unroll
      for (int s = 0; s < 2; s++) {
        int t00 = __builtin_amdgcn_ds_bpermute(srcA, pk[2 * s][0]);
        int t01 = __builtin_amdgcn_ds_bpermute(srcA, pk[2 * s + 1][0]);
        int t10 = __builtin_amdgcn_ds_bpermute(srcA, pk[2 * s][1]);
        int t11 = __builtin_amdgcn_ds_bpermute(srcA, pk[2 * s + 1][1]);
        int t20 = __builtin_amdgcn_ds_bpermute(srcB, pk[2 * s][0]);
        int t21 = __builtin_amdgcn_ds_bpermute(srcB, pk[2 * s + 1][0]);
        int t30 = __builtin_amdgcn_ds_bpermute(srcB, pk[2 * s][1]);
        int t31 = __builtin_amdgcn_ds_bpermute(srcB, pk[2 * s + 1][1]);
        U4 u;
        u.u[0] = hi ? t01 : t00;
        u.u[1] = hi ? t11 : t10;
        u.u[2] = hi ? t21 : t20;
        u.u[3] = hi ? t31 : t30;
        Bf[s] = u.v;
      }
    }
  }

  // ---- head
  float o0 = 0.f, o1 = 0.f, o2 = 0.f;
  #pragma unroll
  for (int m = 0; m < 4; m++) {
    int jb = m * 16 + g * 4;
    const float4* w4 = (const float4*)(W_out1 + jb * 3);
    float4 wa = w4[0], wb = w4[1], wc = w4[2];
    o0 += acc[m][0] * wa.x + acc[m][1] * wa.w + acc[m][2] * wb.z + acc[m][3] * wc.y;
    o1 += acc[m][0] * wa.y + acc[m][1] * wb.x + acc[m][2] * wb.w + acc[m][3] * wc.z;
    o2 += acc[m][0] * wa.z + acc[m][1] * wb.y + acc[m][2] * wc.x + acc[m][3] * wc.w;
  }
  o0 += __shfl_xor(o0, 16, 64); o0 += __shfl_xor(o0, 32, 64);
  o1 += __shfl_xor(o1, 16, 64); o1 += __shfl_xor(o1, 32, 64);
  o2 += __shfl_xor(o2, 16, 64); o2 += __shfl_xor(o2, 32, 64);

  o0 = elu_f(o0); o1 = elu_f(o1); o2 = elu_f(o2);
  float d0 = o0 * W_out2[0] + o1 * W_out2[3] + o2 * W_out2[6];
  float d1 = o0 * W_out2[1] + o1 * W_out2[4] + o2 * W_out2[7];
  float d2 = o0 * W_out2[2] + o1 * W_out2[5] + o2 * W_out2[8];

  float m0 = mp[p * 3 + 0], m1 = mp[p * 3 + 1], m2 = mp[p * 3 + 2];
  float f0 = m0 + d0, f1 = m1 + d1, f2 = m2 + d2;

  size_t ob = ((size_t)b * Pn + p) * 3;
  if (g == 1) { out_disp[ob + 0] = d0; out_disp[ob + 1] = d1; out_disp[ob + 2] = d2; }
  if (g == 2) { out_fp[ob + 0] = f0; out_fp[ob + 1] = f1; out_fp[ob + 2] = f2; }

  const float* R = orient + b * 9;
  float px = R[0] * f0 + R[1] * f1 + R[2] * f2;
  float py = R[3] * f0 + R[4] * f1 + R[5] * f2;

  float a0 = ampvar[p], a1 = ampvar[Pn + p];
  float mx = fmaxf(a0, a1);
  float e0 = __expf(a0 - mx), e1 = __expf(a1 - mx);
  float inv = 1.0f / (e0 + e1);
  float w0 = amp[p] * e0 * inv;
  float w1 = amp[Pn + p] * e1 * inv;

  float pxp = fminf(fmaxf((px + 0.5f) * 256.0f, 0.0f), 254.999f);
  float pyp = fminf(fmaxf((py + 0.5f) * 256.0f, 0.0f), 254.999f);

  if (g == 0) rec[(size_t)b * Pn + p] = make_float4(pxp, pyp, w0, w1);
}

// ---------------- pass B: per-batch 64-bin histogram + exclusive scan -------
__global__ __launch_bounds__(256) void hist_scan_kernel(const float4* __restrict__ rec,
                                                        int* __restrict__ binStart,
                                                        int* __restrict__ binCnt) {
  __shared__ int hist[64];
  int tid = threadIdx.x;
  int b = blockIdx.x;
  if (tid < 64) hist[tid] = 0;
  __syncthreads();
  for (int i = tid; i < Pn; i += 256) {
    float4 r = rec[(size_t)b * Pn + i];
    int bin = (((int)floorf(r.y)) >> 5) * 8 + (((int)floorf(r.x)) >> 5);
    atomicAdd(&hist[bin], 1);
  }
  __syncthreads();
  if (tid == 0) {
    int acc = 0;
    for (int i = 0; i < 64; i++) {
      binStart[b * 64 + i] = acc;
      binCnt[b * 64 + i] = hist[i];
      acc += hist[i];
    }
  }
}

// ---------------- pass C: bin-sort records ----------------
__global__ __launch_bounds__(256) void scatter_kernel(const float4* __restrict__ rec,
                                                      const int* __restrict__ binStart,
                                                      float4* __restrict__ sorted) {
  __shared__ int cursor[64];
  int tid = threadIdx.x;
  int b = blockIdx.x;
  if (tid < 64) cursor[tid] = binStart[b * 64 + tid];
  __syncthreads();
  for (int i = tid; i < Pn; i += 256) {
    float4 r = rec[(size_t)b * Pn + i];
    int bin = (((int)floorf(r.y)) >> 5) * 8 + (((int)floorf(r.x)) >> 5);
    int slot = atomicAdd(&cursor[bin], 1);
    sorted[(size_t)b * Pn + slot] = r;
  }
}

// ---------------- pass D: per-(b,bin) LDS tile splat ----------------
// tile region per (b,bin): 2244 floats = [c][33 rows][34 stride]
__global__ __launch_bounds__(256) void tile_splat_kernel(const float4* __restrict__ sorted,
                                                         const int* __restrict__ binStart,
                                                         const int* __restrict__ binCnt,
                                                         float* __restrict__ tiles) {
  __shared__ float tile[2][33][34];
  int tid = threadIdx.x;
  int blk = blockIdx.x;
  int b = blk >> 6, bin = blk & 63;
  int tx = bin & 7, ty = bin >> 3;
  float* tl = &tile[0][0][0];
  for (int j = tid; j < 2244; j += 256) tl[j] = 0.0f;
  __syncthreads();
  int n = binCnt[b * 64 + bin];
  int base = b * Pn + binStart[b * 64 + bin];
  for (int i = tid; i < n; i += 256) {
    float4 r = sorted[(size_t)base + i];
    int x0 = (int)floorf(r.x), y0 = (int)floorf(r.y);
    float fx = r.x - (float)x0, fy = r.y - (float)y0;
    int lx = x0 - tx * 32, ly = y0 - ty * 32;
    float w00 = (1.f - fx) * (1.f - fy), w10 = fx * (1.f - fy);
    float w01 = (1.f - fx) * fy,         w11 = fx * fy;
    atomicAdd(&tile[0][ly][lx],         r.z * w00);
    atomicAdd(&tile[0][ly][lx + 1],     r.z * w10);
    atomicAdd(&tile[0][ly + 1][lx],     r.z * w01);
    atomicAdd(&tile[0][ly + 1][lx + 1], r.z * w11);
    atomicAdd(&tile[1][ly][lx],         r.w * w00);
    atomicAdd(&tile[1][ly][lx + 1],     r.w * w10);
    atomicAdd(&tile[1][ly + 1][lx],     r.w * w01);
    atomicAdd(&tile[1][ly + 1][lx + 1], r.w * w11);
  }
  __syncthreads();
  float* gbase = tiles + (size_t)blk * 2244;
  for (int j = tid; j < 2244; j += 256) gbase[j] = tl[j];
}

__device__ __forceinline__ float tgv(const float* __restrict__ tiles,
                                     int b, int c, int bin, int r, int cc) {
  return tiles[(size_t)(b * 64 + bin) * 2244 + (c * 33 + r) * 34 + cc];
}

// ---------------- forward FFT along x with tile-gather ----------------
__global__ __launch_bounds__(64) void fft_rows_gather(const float* __restrict__ tiles,
                                                      float2* __restrict__ ws1) {
  __shared__ float re[256], im[256], twr[128], twi[128];
  int lane = threadIdx.x;
  int bc = blockIdx.x >> 8, y = blockIdx.x & 255;
  int b = bc >> 1, c = bc & 1;
  int ty = y >> 5, ry = y & 31;
  for (int t = lane; t < 128; t += 64) {
    float ang = -TWO_PI_F * (float)t / 256.0f;
    twr[t] = cosf(ang); twi[t] = sinf(ang);
  }
  #pragma unroll
  for (int q = 0; q < 4; q++) {
    int x = lane + q * 64;
    int tx = x >> 5, cx = x & 31;
    float v = tgv(tiles, b, c, ty * 8 + tx, ry, cx);
    if (cx == 0 && tx > 0) v += tgv(tiles, b, c, ty * 8 + tx - 1, ry, 32);
    if (ry == 0 && ty > 0) {
      v += tgv(tiles, b, c, (ty - 1) * 8 + tx, 32, cx);
      if (cx == 0 && tx > 0) v += tgv(tiles, b, c, (ty - 1) * 8 + tx - 1, 32, 32);
    }
    re[x] = v; im[x] = 0.0f;
  }
  __syncthreads();
  fft256(re, im, twr, twi, lane, false);
  float2* orow = ws1 + (size_t)bc * 65536 + (size_t)y * 256;
  #pragma unroll
  for (int q = 0; q < 4; q++) {
    int k = lane + q * 64;
    orow[k] = make_float2(re[k], im[k]);
  }
}

// ---------------- in-place per-image 256x256 complex transpose ----------------
__global__ __launch_bounds__(256) void transpose_inplace(float2* __restrict__ data) {
  int img = blockIdx.x, task = blockIdx.y;
  int ti = 0, t = task;
  while (t >= 8 - ti) { t -= 8 - ti; ti++; }
  int tj = ti + t;
  __shared__ float2 ta[32][33];
  __shared__ float2 tb[32][33];
  int lx = threadIdx.x & 31, ly0 = threadIdx.x >> 5;
  float2* base = data + (size_t)img * 65536;
  if (ti == tj) {
    #pragma unroll
    for (int q = 0; q < 4; q++) {
      int ly = ly0 + q * 8;
      ta[ly][lx] = base[(size_t)(ti * 32 + ly) * 256 + ti * 32 + lx];
    }
    __syncthreads();
    #pragma unroll
    for (int q = 0; q < 4; q++) {
      int ly = ly0 + q * 8;
      base[(size_t)(ti * 32 + ly) * 256 + ti * 32 + lx] = ta[lx][ly];
    }
  } else {
    #pragma unroll
    for (int q = 0; q < 4; q++) {
      int ly = ly0 + q * 8;
      ta[ly][lx] = base[(size_t)(ti * 32 + ly) * 256 + tj * 32 + lx];
      tb[ly][lx] = base[(size_t)(tj * 32 + ly) * 256 + ti * 32 + lx];
    }
    __syncthreads();
    #pragma unroll
    for (int q = 0; q < 4; q++) {
      int ly = ly0 + q * 8;
      base[(size_t)(tj * 32 + ly) * 256 + ti * 32 + lx] = ta[lx][ly];
      base[(size_t)(ti * 32 + ly) * 256 + tj * 32 + lx] = tb[lx][ly];
    }
  }
}

// --------- middle: y-FFT both classes, filter-combine, phase_y, inverse y-FFT ----
__global__ __launch_bounds__(64) void fft_mid(const float2* __restrict__ ws1t,
                                              float2* __restrict__ A2,
                                              const float* __restrict__ shift,
                                              const float* __restrict__ Aarr,
                                              const float* __restrict__ Bparr) {
  __shared__ float re0[256], im0[256], re1[256], im1[256], twr[128], twi[128];
  int lane = threadIdx.x;
  int b = blockIdx.x >> 8, kx = blockIdx.x & 255;
  for (int t = lane; t < 128; t += 64) {
    float ang = -TWO_PI_F * (float)t / 256.0f;
    twr[t] = cosf(ang); twi[t] = sinf(ang);
  }
  const float2* r0 = ws1t + ((size_t)b * 2 + 0) * 65536 + (size_t)kx * 256;
  const float2* r1 = ws1t + ((size_t)b * 2 + 1) * 65536 + (size_t)kx * 256;
  #pragma unroll
  for (int q = 0; q < 4; q++) {
    int i = lane + q * 64;
    float2 v0 = r0[i], v1 = r1[i];
    re0[i] = v0.x; im0[i] = v0.y;
    re1[i] = v1.x; im1[i] = v1.y;
  }
  __syncthreads();
  fft256(re0, im0, twr, twi, lane, false);
  fft256(re1, im1, twr, twi, lane, false);

  float A0 = Aarr[0], A1 = Aarr[1], B0 = Bparr[0], B1 = Bparr[1];
  float sy = shift[b * 2 + 1];
  float rx = (kx <= 128) ? (float)kx : (float)(256 - kx);
  #pragma unroll
  for (int q = 0; q < 4; q++) {
    int ky = lane + q * 64;
    float ry = (ky <= 128) ? (float)ky : (float)(256 - ky);
    float R = sqrtf(rx * rx + ry * ry);
    float FF0 = A0 * A0 * __expf(-B0 * B0 * R);
    float FF1 = A1 * A1 * __expf(-B1 * B1 * R);
    float Gr = FF0 * re0[ky] + FF1 * re1[ky];
    float Gi = FF0 * im0[ky] + FF1 * im1[ky];
    float fk = (float)((ky < 128) ? ky : ky - 256) / 256.0f;
    float th = -TWO_PI_F * fk * sy;
    float c = __cosf(th), s = __sinf(th);
    re0[ky] = Gr * c - Gi * s;
    im0[ky] = Gr * s + Gi * c;
  }
  __syncthreads();
  fft256(re0, im0, twr, twi, lane, true);
  const float inv = 1.0f / 256.0f;
  float2* orow = A2 + (size_t)b * 65536 + (size_t)kx * 256;
  #pragma unroll
  for (int q = 0; q < 4; q++) {
    int yy = lane + q * 64;
    orow[yy] = make_float2(re0[yy] * inv, im0[yy] * inv);
  }
}

// --------- final: phase_x, inverse x-FFT, write real ----------
__global__ __launch_bounds__(64) void fft_final(const float2* __restrict__ A2t,
                                                const float* __restrict__ shift,
                                                float* __restrict__ out_imgs) {
  __shared__ float re[256], im[256], twr[128], twi[128];
  int lane = threadIdx.x;
  int b = blockIdx.x >> 8, y = blockIdx.x & 255;
  for (int t = lane; t < 128; t += 64) {
    float ang = -TWO_PI_F * (float)t / 256.0f;
    twr[t] = cosf(ang); twi[t] = sinf(ang);
  }
  const float2* row = A2t + (size_t)b * 65536 + (size_t)y * 256;
  float sx = shift[b * 2 + 0];
  #pragma unroll
  for (int q = 0; q < 4; q++) {
    int k = lane + q * 64;
    float2 v = row[k];
    float fk = (float)((k < 128) ? k : k - 256) / 256.0f;
    float th = -TWO_PI_F * fk * sx;
    float c = __cosf(th), s = __sinf(th);
    re[k] = v.x * c - v.y * s;
    im[k] = v.x * s + v.y * c;
  }
  __syncthreads();
  fft256(re, im, twr, twi, lane, true);
  const float inv = 1.0f / 256.0f;
  float* orow = out_imgs + (size_t)b * 65536 + (size_t)y * 256;
  #pragma unroll
  for (int q = 0; q < 4; q++) {
    int x = lane + q * 64;
    orow[x] = re[x] * inv;
  }
}

// ---------------- launch ----------------
extern "C" void kernel_launch(void* const* d_in, const int* in_sizes, int n_in,
                              void* d_out, int out_size, void* d_ws, size_t ws_size,
                              hipStream_t stream) {
  (void)in_sizes; (void)n_in; (void)out_size; (void)ws_size;
  const float* z       = (const float*)d_in[0];
  const float* orient  = (const float*)d_in[1];
  const float* shift   = (const float*)d_in[2];
  const float* mp      = (const float*)d_in[3];
  const float* W_in    = (const float*)d_in[4];
  const float* W_layers= (const float*)d_in[5];
  const float* W_out1  = (const float*)d_in[6];
  const float* W_out2  = (const float*)d_in[7];
  const float* amp     = (const float*)d_in[8];
  const float* ampvar  = (const float*)d_in[9];
  const float* Aarr    = (const float*)d_in[10];
  const float* Bparr   = (const float*)d_in[11];

  char* ws = (char*)d_ws;
  // off 0 region (sequential lifetimes): encpart (4MB, enc->A) -> tiles
  // (18.4MB, D->fft_rows) -> A2 (16MB, fft_mid->fft_final)
  float*  encpart = (float*)ws;
  float*  tiles   = (float*)ws;
  float2* A2      = (float2*)ws;
  // off 20MB region: ws1 (32MB, fft_rows->fft_mid). Earlier-phase buffers
  // (rec/sorted/zpart/Wfrag/hist) alias inside it; all dead before fft_rows.
  char* wsB = ws + (20u << 20);
  float2* ws1     = (float2*)wsB;
  float4* rec     = (float4*)wsB;                                   // 8 MB
  float4* sorted  = (float4*)(wsB + (8u << 20));                    // 8 MB
  float*  zpart   = (float*)(wsB + (16u << 20));                    // 8 KB
  unsigned short* Wfrag = (unsigned short*)(wsB + (16u << 20) + 8192); // 32 KB
  int* binStart   = (int*)(wsB + (17u << 20));                      // 8 KB
  int* binCnt     = (int*)(wsB + (17u << 20) + 8192);               // 8 KB

  float* out      = (float*)d_out;
  float* out_imgs = out;                               // [B][S][S]
  float* out_fp   = out + (size_t)Bn * Sn * Sn;        // [B][P][3]
  float* out_disp = out_fp + (size_t)Bn * Pn * 3;      // [B][P][3]

  enc_kernel<<<Pn / 64, 64, 0, stream>>>(mp, W_in, encpart);
  prep_kernel<<<16, 256, 0, stream>>>(z, W_in, W_layers, zpart, Wfrag);
  mlp_mfma16_kernel<<<(Bn * Pn / 16) / 4, 256, 0, stream>>>(
      encpart, zpart, Wfrag, W_out1, W_out2, mp, orient, amp, ampvar,
      rec, out_fp, out_disp);
  hist_scan_kernel<<<Bn, 256, 0, stream>>>(rec, binStart, binCnt);
  scatter_kernel<<<Bn, 256, 0, stream>>>(rec, binStart, sorted);
  tile_splat_kernel<<<Bn * 64, 256, 0, stream>>>(sorted, binStart, binCnt, tiles);
  fft_rows_gather<<<Bn * Cn * Sn, 64, 0, stream>>>(tiles, ws1);
  transpose_inplace<<<dim3(Bn * Cn, 36), 256, 0, stream>>>(ws1);
  fft_mid<<<Bn * Sn, 64, 0, stream>>>(ws1, A2, shift, Aarr, Bparr);
  transpose_inplace<<<dim3(Bn, 36), 256, 0, stream>>>(A2);
  fft_final<<<Bn * Sn, 64, 0, stream>>>(A2, shift, out_imgs);
}